// Round 6
// baseline (1176.321 us; speedup 1.0000x reference)
//
#include <hip/hip_runtime.h>
#include <hip/hip_bf16.h>

#define DIMN 1024
#define NH 16
#define HD 64
#define SEQ 2048
#define BATCH 2
#define BHN (BATCH*NH)        // 32
#define MROWS (BATCH*SEQ)     // 4096
#define KKEEP 409
#define SCALEF 0.125f
#define QROWS 8               // q-rows per block
#define SROW 2052             // padded S row stride (floats); 8208 B, %32 banks = +4
#define SROWB 8208

typedef __attribute__((ext_vector_type(8))) short short8;
typedef __attribute__((ext_vector_type(4))) short short4v;
typedef __attribute__((ext_vector_type(4))) float f32x4;

#define MFMA(a,b,c) __builtin_amdgcn_mfma_f32_16x16x32_bf16(a,b,c,0,0,0)

static __device__ __forceinline__ short f2bf(float f) {
    __hip_bfloat16 h = __float2bfloat16(f);
    return *reinterpret_cast<short*>(&h);
}
static __device__ __forceinline__ float bf2f(short s) {
    __hip_bfloat16 h = *reinterpret_cast<__hip_bfloat16*>(&s);
    return __bfloat162float(h);
}
static __device__ __forceinline__ short8 ld8(const short* p) {
    return *reinterpret_cast<const short8*>(p);
}

// ---------------- K0a: fp32 -> (hi, lo) bf16 pair --------------------------
__global__ void conv_hilo(const float* __restrict__ in,
                          short* __restrict__ hi, short* __restrict__ lo, int n) {
    const int n4 = n >> 2;
    for (int i = blockIdx.x * blockDim.x + threadIdx.x; i < n4;
         i += gridDim.x * blockDim.x) {
        float4 v = reinterpret_cast<const float4*>(in)[i];
        short4v h, l;
        #pragma unroll
        for (int j = 0; j < 4; ++j) {
            float f = (&v.x)[j];
            short hb = f2bf(f);
            h[j] = hb;
            l[j] = f2bf(f - bf2f(hb));
        }
        reinterpret_cast<short4v*>(hi)[i] = h;
        reinterpret_cast<short4v*>(lo)[i] = l;
    }
}

// ---------------- K0b: fp32 -> bf16 ----------------------------------------
__global__ void conv_bf16(const float* __restrict__ in, short* __restrict__ out, int n) {
    const int n4 = n >> 2;
    for (int i = blockIdx.x * blockDim.x + threadIdx.x; i < n4;
         i += gridDim.x * blockDim.x) {
        float4 v = reinterpret_cast<const float4*>(in)[i];
        short4v o;
        o[0] = f2bf(v.x); o[1] = f2bf(v.y); o[2] = f2bf(v.z); o[3] = f2bf(v.w);
        reinterpret_cast<short4v*>(out)[i] = o;
    }
}

// ---------------- K1: Q/K projection, hi/lo precision ----------------------
__global__ __launch_bounds__(256) void qk_mfma(
    const short* __restrict__ xh, const short* __restrict__ xl,
    const short* __restrict__ wqh, const short* __restrict__ wql, const float* __restrict__ bq,
    const short* __restrict__ wkh, const short* __restrict__ wkl, const float* __restrict__ bk,
    short* __restrict__ qhi, short* __restrict__ qlo,
    short* __restrict__ khi, short* __restrict__ klo)
{
    const int z = blockIdx.z;
    const short* wh = z ? wkh : wqh;
    const short* wl = z ? wkl : wql;
    const float* bias = z ? bk : bq;
    short* dhi = z ? khi : qhi;
    short* dlo = z ? klo : qlo;

    const int tid  = threadIdx.x;
    const int wv_  = tid >> 6, lane = tid & 63;
    const int r    = lane & 15, kg = lane >> 4;
    const int m_base = blockIdx.x * 128 + wv_ * 32;
    const int n_base = blockIdx.y * 64;

    f32x4 acc[2][4] = {};

    for (int ks = 0; ks < 32; ++ks) {
        const int k0 = ks * 32 + kg * 8;
        short8 ah0 = ld8(xh + (size_t)(m_base + r) * DIMN + k0);
        short8 al0 = ld8(xl + (size_t)(m_base + r) * DIMN + k0);
        short8 ah1 = ld8(xh + (size_t)(m_base + 16 + r) * DIMN + k0);
        short8 al1 = ld8(xl + (size_t)(m_base + 16 + r) * DIMN + k0);
        #pragma unroll
        for (int nf = 0; nf < 4; ++nf) {
            short8 bh = ld8(wh + (size_t)(n_base + nf * 16 + r) * DIMN + k0);
            short8 bl = ld8(wl + (size_t)(n_base + nf * 16 + r) * DIMN + k0);
            acc[0][nf] = MFMA(ah0, bh, acc[0][nf]);
            acc[0][nf] = MFMA(ah0, bl, acc[0][nf]);
            acc[0][nf] = MFMA(al0, bh, acc[0][nf]);
            acc[1][nf] = MFMA(ah1, bh, acc[1][nf]);
            acc[1][nf] = MFMA(ah1, bl, acc[1][nf]);
            acc[1][nf] = MFMA(al1, bh, acc[1][nf]);
        }
    }

    const int h = blockIdx.y;
    #pragma unroll
    for (int mf = 0; mf < 2; ++mf)
        #pragma unroll
        for (int nf = 0; nf < 4; ++nf)
            #pragma unroll
            for (int i = 0; i < 4; ++i) {
                const int m  = m_base + mf * 16 + kg * 4 + i;
                const int nn = n_base + nf * 16 + r;
                const float val = acc[mf][nf][i] + bias[nn];
                const int b_ = m >> 11, s = m & 2047;
                const size_t idx = (((size_t)(b_ * NH + h)) * SEQ + s) * HD + nf * 16 + r;
                const short hb = f2bf(val);
                dhi[idx] = hb;
                dlo[idx] = f2bf(val - bf2f(hb));
            }
}

// ---------------- K2: V projection (2-MFMA), transposed output -------------
__global__ __launch_bounds__(256) void v_mfma(
    const short* __restrict__ xh, const short* __restrict__ xl,
    const short* __restrict__ wvb, const float* __restrict__ bv,
    short* __restrict__ vt)
{
    const int tid  = threadIdx.x;
    const int wv_  = tid >> 6, lane = tid & 63;
    const int r    = lane & 15, kg = lane >> 4;
    const int m_base = blockIdx.x * 128 + wv_ * 32;
    const int n_base = blockIdx.y * 64;

    f32x4 acc[2][4] = {};

    for (int ks = 0; ks < 32; ++ks) {
        const int k0 = ks * 32 + kg * 8;
        short8 ah0 = ld8(xh + (size_t)(m_base + r) * DIMN + k0);
        short8 al0 = ld8(xl + (size_t)(m_base + r) * DIMN + k0);
        short8 ah1 = ld8(xh + (size_t)(m_base + 16 + r) * DIMN + k0);
        short8 al1 = ld8(xl + (size_t)(m_base + 16 + r) * DIMN + k0);
        #pragma unroll
        for (int nf = 0; nf < 4; ++nf) {
            short8 b = ld8(wvb + (size_t)(n_base + nf * 16 + r) * DIMN + k0);
            acc[0][nf] = MFMA(ah0, b, acc[0][nf]);
            acc[0][nf] = MFMA(al0, b, acc[0][nf]);
            acc[1][nf] = MFMA(ah1, b, acc[1][nf]);
            acc[1][nf] = MFMA(al1, b, acc[1][nf]);
        }
    }

    const int h = blockIdx.y;
    #pragma unroll
    for (int mf = 0; mf < 2; ++mf)
        #pragma unroll
        for (int nf = 0; nf < 4; ++nf)
            #pragma unroll
            for (int i = 0; i < 4; ++i) {
                const int m  = m_base + mf * 16 + kg * 4 + i;
                const int nn = n_base + nf * 16 + r;
                const float val = acc[mf][nf][i] + bv[nn];
                const int b_ = m >> 11, s = m & 2047;
                vt[(((size_t)(b_ * NH + h)) * HD + nf * 16 + r) * SEQ + s] = f2bf(val);
            }
}

// ---------------- K3: fused scores + exact top-k + softmax + PV ------------
// 512 threads = 8 waves; 8 q-rows per block; ~68 KB LDS -> 2 blocks/CU so the
// VALU-only radix phase of one block co-schedules with the MFMA/VMEM phases
// of the other block on the same CU.
__global__ __launch_bounds__(512, 4) void fused_attn(
    const short* __restrict__ qh, const short* __restrict__ ql,
    const short* __restrict__ kh, const short* __restrict__ kl,
    const short* __restrict__ vtb, float* __restrict__ attn,
    short* __restrict__ ctxb)
{
    __shared__ float S[QROWS * SROW];   // 65.7 KB fp32 scores; bf16 P in-place
    __shared__ float CT[QROWS][64];     // 2 KB partial ctx (upper k-half)

    const int tid = threadIdx.x;
    const int w   = tid >> 6, lane = tid & 63;
    const int r   = lane & 15, kg = lane >> 4;
    const int bh  = blockIdx.y;
    const int q0  = blockIdx.x * QROWS;

    // ---- Phase A: S = SCALE * Q K^T, hi/lo 3-MFMA precision ----
    // A-fragment rows 8-15 duplicate rows 0-7 (only 8 q-rows); outputs from
    // kg>=2 lanes are duplicates and are not written.
    const size_t qoff = ((size_t)bh * SEQ + q0 + (r & 7)) * HD + kg * 8;
    short8 a0h = ld8(qh + qoff),      a0l = ld8(ql + qoff);
    short8 a1h = ld8(qh + qoff + 32), a1l = ld8(ql + qoff + 32);
    for (int t = 0; t < 16; ++t) {
        const int j0 = (w + 8 * t) * 16;
        const size_t koff = ((size_t)bh * SEQ + j0 + r) * HD + kg * 8;
        short8 b0h = ld8(kh + koff),      b0l = ld8(kl + koff);
        short8 b1h = ld8(kh + koff + 32), b1l = ld8(kl + koff + 32);
        f32x4 accA = {0.f, 0.f, 0.f, 0.f};     // two independent 3-chains
        f32x4 accB = {0.f, 0.f, 0.f, 0.f};
        accA = MFMA(a0h, b0h, accA);
        accB = MFMA(a1h, b1h, accB);
        accA = MFMA(a0h, b0l, accA);
        accB = MFMA(a1h, b1l, accB);
        accA = MFMA(a0l, b0h, accA);
        accB = MFMA(a1l, b1h, accB);
        if (kg < 2) {
            #pragma unroll
            for (int i = 0; i < 4; ++i)
                S[(kg * 4 + i) * SROW + j0 + r] = (accA[i] + accB[i]) * SCALEF;
        }
    }
    __syncthreads();

    // ---- Phase B: exact 32-bit radix top-k (ballot counting) + softmax ----
    // one row per wave; lane holds j = lane*4 + (jj&3) + (jj>>2)*256
    {
        const int row = w;
        float vals[32]; unsigned u[32];
        const float* Srow = &S[row * SROW];
        #pragma unroll
        for (int g = 0; g < 8; ++g) {
            f32x4 v4 = *reinterpret_cast<const f32x4*>(Srow + lane * 4 + g * 256);
            #pragma unroll
            for (int q_ = 0; q_ < 4; ++q_) vals[g * 4 + q_] = v4[q_];
        }
        #pragma unroll
        for (int jj = 0; jj < 32; ++jj) {
            unsigned fu = __float_as_uint(vals[jj]);
            u[jj] = (fu & 0x80000000u) ? ~fu : (fu | 0x80000000u);
        }
        unsigned cur = 0;
        for (int bit = 31; bit >= 0; --bit) {
            const unsigned cand = cur | (1u << bit);
            int c = 0;
            #pragma unroll
            for (int jj = 0; jj < 32; ++jj)
                c += __popcll(__ballot(u[jj] >= cand));
            if (c >= KKEEP) cur = cand;
        }
        float m = -3.0e38f;
        #pragma unroll
        for (int jj = 0; jj < 32; ++jj) m = fmaxf(m, vals[jj]);
        #pragma unroll
        for (int off = 32; off; off >>= 1) m = fmaxf(m, __shfl_xor(m, off));
        float denom = 0.f;
        #pragma unroll
        for (int jj = 0; jj < 32; ++jj) {
            const float e = (u[jj] >= cur) ? __expf(vals[jj] - m) : 0.f;
            vals[jj] = e; denom += e;
        }
        #pragma unroll
        for (int off = 32; off; off >>= 1) denom += __shfl_xor(denom, off);
        const float inv = 1.0f / denom;

        float* arow = attn + ((size_t)bh * SEQ + q0 + row) * SEQ + lane * 4;
        char* Sb = (char*)&S[row * SROW];
        const int swz = (row & 7) << 4;
        #pragma unroll
        for (int g = 0; g < 8; ++g) {
            const float p0 = vals[g * 4 + 0] * inv, p1 = vals[g * 4 + 1] * inv;
            const float p2 = vals[g * 4 + 2] * inv, p3 = vals[g * 4 + 3] * inv;
            f32x4 pv = {p0, p1, p2, p3};
            __builtin_nontemporal_store(pv, reinterpret_cast<f32x4*>(arow + g * 256));
            short4v pb;
            pb[0] = f2bf(p0); pb[1] = f2bf(p1); pb[2] = f2bf(p2); pb[3] = f2bf(p3);
            *reinterpret_cast<short4v*>(Sb + ((lane * 8 + g * 512) ^ swz)) = pb;
        }
    }
    __syncthreads();

    // ---- Phase C: ctx = P @ V; 8 waves = 4 col-groups x 2 k-halves ----
    // P rows 8-15 of the A-fragment duplicate rows 0-7; kg>=2 outputs unused.
    const int c0 = (w & 3) * 16;
    const int kh_ = w >> 2;
    f32x4 acc0 = {0.f, 0.f, 0.f, 0.f};
    f32x4 acc1 = {0.f, 0.f, 0.f, 0.f};
    const short* vp = vtb + ((size_t)bh * HD + c0 + r) * SEQ + kh_ * 1024;
    const int swzr = (r & 7) << 4;
    const char* SrowB = (const char*)&S[(r & 7) * SROW];
    for (int ks = 0; ks < 32; ks += 2) {
        const int kk0 = kh_ * 32 + ks, kk1 = kk0 + 1;
        short8 pa0 = *reinterpret_cast<const short8*>(
            SrowB + ((kk0 * 64 + kg * 16) ^ swzr));
        short8 pa1 = *reinterpret_cast<const short8*>(
            SrowB + ((kk1 * 64 + kg * 16) ^ swzr));
        short8 vb0 = ld8(vp + ks * 32 + kg * 8);
        short8 vb1 = ld8(vp + ks * 32 + 32 + kg * 8);
        acc0 = MFMA(pa0, vb0, acc0);
        acc1 = MFMA(pa1, vb1, acc1);
    }
    acc0[0] += acc1[0]; acc0[1] += acc1[1];
    acc0[2] += acc1[2]; acc0[3] += acc1[3];
    if (kh_ == 1 && kg < 2) {
        #pragma unroll
        for (int i = 0; i < 4; ++i) CT[kg * 4 + i][c0 + r] = acc0[i];
    }
    __syncthreads();
    if (kh_ == 0 && kg < 2) {
        #pragma unroll
        for (int i = 0; i < 4; ++i) {
            const float val = acc0[i] + CT[kg * 4 + i][c0 + r];
            ctxb[((size_t)bh * SEQ + q0 + kg * 4 + i) * HD + c0 + r] = f2bf(val);
        }
    }
}

// ---------------- K4: out = ctx @ wo^T + bo (fp32 out) ---------------------
__global__ __launch_bounds__(256) void out_mfma(
    const short* __restrict__ ctxb, const short* __restrict__ wob,
    const float* __restrict__ bo, float* __restrict__ out)
{
    const int tid = threadIdx.x;
    const int w_  = tid >> 6, lane = tid & 63;
    const int r   = lane & 15, kg = lane >> 4;
    const int m_base = blockIdx.x * 128 + w_ * 32;
    const int n_base = blockIdx.y * 64;

    f32x4 acc[2][4] = {};

    for (int ks = 0; ks < 32; ++ks) {
        const int k0 = ks * 32 + kg * 8;
        const int h = k0 >> 6, hd = k0 & 63;
        short8 a[2];
        #pragma unroll
        for (int mf = 0; mf < 2; ++mf) {
            const int m = m_base + mf * 16 + r;
            const int b_ = m >> 11, s = m & 2047;
            a[mf] = ld8(ctxb + (((size_t)(b_ * NH + h)) * SEQ + s) * HD + hd);
        }
        #pragma unroll
        for (int nf = 0; nf < 4; ++nf) {
            short8 b = ld8(wob + (size_t)(n_base + nf * 16 + r) * DIMN + k0);
            acc[0][nf] = MFMA(a[0], b, acc[0][nf]);
            acc[1][nf] = MFMA(a[1], b, acc[1][nf]);
        }
    }

    #pragma unroll
    for (int mf = 0; mf < 2; ++mf)
        #pragma unroll
        for (int nf = 0; nf < 4; ++nf)
            #pragma unroll
            for (int i = 0; i < 4; ++i) {
                const int m  = m_base + mf * 16 + kg * 4 + i;
                const int nn = n_base + nf * 16 + r;
                out[(size_t)m * DIMN + nn] = acc[mf][nf][i] + bo[nn];
            }
}

extern "C" void kernel_launch(void* const* d_in, const int* in_sizes, int n_in,
                              void* d_out, int out_size, void* d_ws, size_t ws_size,
                              hipStream_t stream) {
    const float* x  = (const float*)d_in[0];
    const float* wq = (const float*)d_in[1];
    const float* bq = (const float*)d_in[2];
    const float* wk = (const float*)d_in[3];
    const float* bk = (const float*)d_in[4];
    const float* wv = (const float*)d_in[5];
    const float* bv = (const float*)d_in[6];
    const float* wo = (const float*)d_in[7];
    const float* bo = (const float*)d_in[8];

    float* out  = (float*)d_out;
    float* attn = out + (size_t)MROWS * DIMN;   // 512 MB region, written by fused_attn

    // --- scratch that dies before fused_attn runs: lives in the attn region ---
    short* xhi = (short*)attn;
    short* xlo = xhi + (size_t)MROWS * DIMN;
    short* wqh = xlo + (size_t)MROWS * DIMN;
    short* wql = wqh + (size_t)DIMN * DIMN;
    short* wkh = wql + (size_t)DIMN * DIMN;
    short* wkl = wkh + (size_t)DIMN * DIMN;
    short* wvb = wkl + (size_t)DIMN * DIMN;

    // --- scratch that must survive into/past fused_attn: lives in d_ws ---
    const size_t QKV = (size_t)BHN * SEQ * HD;  // 4,194,304
    short* qhi = (short*)d_ws;
    short* qlo = qhi + QKV;
    short* khi = qlo + QKV;
    short* klo = khi + QKV;
    short* vt  = klo + QKV;
    short* ctx = vt  + QKV;
    short* wob = ctx + QKV;

    conv_hilo<<<1024, 256, 0, stream>>>(x,  xhi, xlo, MROWS * DIMN);
    conv_hilo<<<512,  256, 0, stream>>>(wq, wqh, wql, DIMN * DIMN);
    conv_hilo<<<512,  256, 0, stream>>>(wk, wkh, wkl, DIMN * DIMN);
    conv_bf16<<<512,  256, 0, stream>>>(wv, wvb, DIMN * DIMN);
    conv_bf16<<<512,  256, 0, stream>>>(wo, wob, DIMN * DIMN);

    qk_mfma<<<dim3(MROWS / 128, DIMN / 64, 2), 256, 0, stream>>>(
        xhi, xlo, wqh, wql, bq, wkh, wkl, bk, qhi, qlo, khi, klo);
    v_mfma<<<dim3(MROWS / 128, DIMN / 64), 256, 0, stream>>>(
        xhi, xlo, wvb, bv, vt);

    fused_attn<<<dim3(SEQ / QROWS, BHN), 512, 0, stream>>>(
        qhi, qlo, khi, klo, vt, attn, ctx);

    out_mfma<<<dim3(MROWS / 128, DIMN / 64), 256, 0, stream>>>(ctx, wob, bo, out);
}

// Round 7
// 886.207 us; speedup vs baseline: 1.3274x; 1.3274x over previous
//
#include <hip/hip_runtime.h>
#include <hip/hip_bf16.h>

#define DIMN 1024
#define NH 16
#define HD 64
#define SEQ 2048
#define BATCH 2
#define BHN (BATCH*NH)        // 32
#define MROWS (BATCH*SEQ)     // 4096
#define KKEEP 409
#define SCALEF 0.125f
#define QROWS 32              // q-rows per block
#define CBROW 516             // chunk-buffer row stride (floats)

typedef __attribute__((ext_vector_type(8))) short short8;
typedef __attribute__((ext_vector_type(4))) short short4v;
typedef __attribute__((ext_vector_type(4))) float f32x4;

#define MFMA(a,b,c) __builtin_amdgcn_mfma_f32_16x16x32_bf16(a,b,c,0,0,0)

static __device__ __forceinline__ short f2bf(float f) {
    __hip_bfloat16 h = __float2bfloat16(f);
    return *reinterpret_cast<short*>(&h);
}
static __device__ __forceinline__ float bf2f(short s) {
    __hip_bfloat16 h = *reinterpret_cast<__hip_bfloat16*>(&s);
    return __bfloat162float(h);
}
static __device__ __forceinline__ short8 ld8(const short* p) {
    return *reinterpret_cast<const short8*>(p);
}
// inverse of the monotone float->uint key map
static __device__ __forceinline__ float keyf(unsigned u) {
    unsigned fu = (u & 0x80000000u) ? (u ^ 0x80000000u) : ~u;
    return __uint_as_float(fu);
}

// ---------------- K0a: fp32 -> (hi, lo) bf16 pair --------------------------
__global__ void conv_hilo(const float* __restrict__ in,
                          short* __restrict__ hi, short* __restrict__ lo, int n) {
    const int n4 = n >> 2;
    for (int i = blockIdx.x * blockDim.x + threadIdx.x; i < n4;
         i += gridDim.x * blockDim.x) {
        float4 v = reinterpret_cast<const float4*>(in)[i];
        short4v h, l;
        #pragma unroll
        for (int j = 0; j < 4; ++j) {
            float f = (&v.x)[j];
            short hb = f2bf(f);
            h[j] = hb;
            l[j] = f2bf(f - bf2f(hb));
        }
        reinterpret_cast<short4v*>(hi)[i] = h;
        reinterpret_cast<short4v*>(lo)[i] = l;
    }
}

// ---------------- K0b: fp32 -> bf16 ----------------------------------------
__global__ void conv_bf16(const float* __restrict__ in, short* __restrict__ out, int n) {
    const int n4 = n >> 2;
    for (int i = blockIdx.x * blockDim.x + threadIdx.x; i < n4;
         i += gridDim.x * blockDim.x) {
        float4 v = reinterpret_cast<const float4*>(in)[i];
        short4v o;
        o[0] = f2bf(v.x); o[1] = f2bf(v.y); o[2] = f2bf(v.z); o[3] = f2bf(v.w);
        reinterpret_cast<short4v*>(out)[i] = o;
    }
}

// ---------------- K1: Q/K projection, hi/lo precision ----------------------
__global__ __launch_bounds__(256) void qk_mfma(
    const short* __restrict__ xh, const short* __restrict__ xl,
    const short* __restrict__ wqh, const short* __restrict__ wql, const float* __restrict__ bq,
    const short* __restrict__ wkh, const short* __restrict__ wkl, const float* __restrict__ bk,
    short* __restrict__ qhi, short* __restrict__ qlo,
    short* __restrict__ khi, short* __restrict__ klo)
{
    const int z = blockIdx.z;
    const short* wh = z ? wkh : wqh;
    const short* wl = z ? wkl : wql;
    const float* bias = z ? bk : bq;
    short* dhi = z ? khi : qhi;
    short* dlo = z ? klo : qlo;

    const int tid  = threadIdx.x;
    const int wv_  = tid >> 6, lane = tid & 63;
    const int r    = lane & 15, kg = lane >> 4;
    const int m_base = blockIdx.x * 128 + wv_ * 32;
    const int n_base = blockIdx.y * 64;

    f32x4 acc[2][4] = {};

    for (int ks = 0; ks < 32; ++ks) {
        const int k0 = ks * 32 + kg * 8;
        short8 ah0 = ld8(xh + (size_t)(m_base + r) * DIMN + k0);
        short8 al0 = ld8(xl + (size_t)(m_base + r) * DIMN + k0);
        short8 ah1 = ld8(xh + (size_t)(m_base + 16 + r) * DIMN + k0);
        short8 al1 = ld8(xl + (size_t)(m_base + 16 + r) * DIMN + k0);
        #pragma unroll
        for (int nf = 0; nf < 4; ++nf) {
            short8 bh = ld8(wh + (size_t)(n_base + nf * 16 + r) * DIMN + k0);
            short8 bl = ld8(wl + (size_t)(n_base + nf * 16 + r) * DIMN + k0);
            acc[0][nf] = MFMA(ah0, bh, acc[0][nf]);
            acc[0][nf] = MFMA(ah0, bl, acc[0][nf]);
            acc[0][nf] = MFMA(al0, bh, acc[0][nf]);
            acc[1][nf] = MFMA(ah1, bh, acc[1][nf]);
            acc[1][nf] = MFMA(ah1, bl, acc[1][nf]);
            acc[1][nf] = MFMA(al1, bh, acc[1][nf]);
        }
    }

    const int h = blockIdx.y;
    #pragma unroll
    for (int mf = 0; mf < 2; ++mf)
        #pragma unroll
        for (int nf = 0; nf < 4; ++nf)
            #pragma unroll
            for (int i = 0; i < 4; ++i) {
                const int m  = m_base + mf * 16 + kg * 4 + i;
                const int nn = n_base + nf * 16 + r;
                const float val = acc[mf][nf][i] + bias[nn];
                const int b_ = m >> 11, s = m & 2047;
                const size_t idx = (((size_t)(b_ * NH + h)) * SEQ + s) * HD + nf * 16 + r;
                const short hb = f2bf(val);
                dhi[idx] = hb;
                dlo[idx] = f2bf(val - bf2f(hb));
            }
}

// ---------------- K2: V projection (2-MFMA), transposed output -------------
__global__ __launch_bounds__(256) void v_mfma(
    const short* __restrict__ xh, const short* __restrict__ xl,
    const short* __restrict__ wvb, const float* __restrict__ bv,
    short* __restrict__ vt)
{
    const int tid  = threadIdx.x;
    const int wv_  = tid >> 6, lane = tid & 63;
    const int r    = lane & 15, kg = lane >> 4;
    const int m_base = blockIdx.x * 128 + wv_ * 32;
    const int n_base = blockIdx.y * 64;

    f32x4 acc[2][4] = {};

    for (int ks = 0; ks < 32; ++ks) {
        const int k0 = ks * 32 + kg * 8;
        short8 ah0 = ld8(xh + (size_t)(m_base + r) * DIMN + k0);
        short8 al0 = ld8(xl + (size_t)(m_base + r) * DIMN + k0);
        short8 ah1 = ld8(xh + (size_t)(m_base + 16 + r) * DIMN + k0);
        short8 al1 = ld8(xl + (size_t)(m_base + 16 + r) * DIMN + k0);
        #pragma unroll
        for (int nf = 0; nf < 4; ++nf) {
            short8 b = ld8(wvb + (size_t)(n_base + nf * 16 + r) * DIMN + k0);
            acc[0][nf] = MFMA(ah0, b, acc[0][nf]);
            acc[0][nf] = MFMA(al0, b, acc[0][nf]);
            acc[1][nf] = MFMA(ah1, b, acc[1][nf]);
            acc[1][nf] = MFMA(al1, b, acc[1][nf]);
        }
    }

    const int h = blockIdx.y;
    #pragma unroll
    for (int mf = 0; mf < 2; ++mf)
        #pragma unroll
        for (int nf = 0; nf < 4; ++nf)
            #pragma unroll
            for (int i = 0; i < 4; ++i) {
                const int m  = m_base + mf * 16 + kg * 4 + i;
                const int nn = n_base + nf * 16 + r;
                const float val = acc[mf][nf][i] + bv[nn];
                const int b_ = m >> 11, s = m & 2047;
                vt[(((size_t)(b_ * NH + h)) * HD + nf * 16 + r) * SEQ + s] = f2bf(val);
            }
}

// ---------------- K3: fused scores + exact top-k + softmax + PV ------------
// 1024 threads = 16 waves; 32 q-rows per block. Scores live in REGISTER keys
// (u[2][32] per wave via chunked LDS transpose); LDS holds only the chunk
// staging buffer (66 KB), then bf16 P (128 KB, same union) + CT (24 KB).
__global__ __launch_bounds__(1024, 4) void fused_attn(
    const short* __restrict__ qh, const short* __restrict__ ql,
    const short* __restrict__ kh, const short* __restrict__ kl,
    const short* __restrict__ vtb, float* __restrict__ attn,
    short* __restrict__ ctxb)
{
    __shared__ __align__(16) char smem[131072 + 24576];  // union(CB,P) + CT
    float* CB = (float*)smem;                 // [32][CBROW] fp32 chunk
    float* CT = (float*)(smem + 131072);      // [3][32][64] fp32 partials

    const int tid = threadIdx.x;
    const int w   = tid >> 6, lane = tid & 63;
    const int r   = lane & 15, kg = lane >> 4;
    const int bh  = blockIdx.y;
    const int q0  = blockIdx.x * QROWS;

    // ---- Phase A: S = SCALE*Q K^T in 4 chunks of 512 cols; keys -> regs ----
    short8 a0h[2], a0l[2], a1h[2], a1l[2];
    #pragma unroll
    for (int rg = 0; rg < 2; ++rg) {
        const size_t qoff = ((size_t)bh * SEQ + q0 + rg * 16 + r) * HD + kg * 8;
        a0h[rg] = ld8(qh + qoff);      a0l[rg] = ld8(ql + qoff);
        a1h[rg] = ld8(qh + qoff + 32); a1l[rg] = ld8(ql + qoff + 32);
    }
    unsigned u[2][32];

    for (int c = 0; c < 4; ++c) {
        #pragma unroll
        for (int tt = 0; tt < 2; ++tt) {
            const int j0c = (w + 16 * tt) * 16;
            const size_t koff = ((size_t)bh * SEQ + c * 512 + j0c + r) * HD + kg * 8;
            short8 b0h = ld8(kh + koff),      b0l = ld8(kl + koff);
            short8 b1h = ld8(kh + koff + 32), b1l = ld8(kl + koff + 32);
            #pragma unroll
            for (int rg = 0; rg < 2; ++rg) {
                f32x4 accA = {0.f, 0.f, 0.f, 0.f};
                f32x4 accB = {0.f, 0.f, 0.f, 0.f};
                accA = MFMA(a0h[rg], b0h, accA);
                accB = MFMA(a1h[rg], b1h, accB);
                accA = MFMA(a0h[rg], b0l, accA);
                accB = MFMA(a1h[rg], b1l, accB);
                accA = MFMA(a0l[rg], b0h, accA);
                accB = MFMA(a1l[rg], b1h, accB);
                #pragma unroll
                for (int i = 0; i < 4; ++i)
                    CB[(rg * 16 + kg * 4 + i) * CBROW + j0c + r] =
                        (accA[i] + accB[i]) * SCALEF;
            }
        }
        __syncthreads();
        // pull this wave's 2 rows' 512-col slice into register keys
        #pragma unroll
        for (int rr = 0; rr < 2; ++rr) {
            const float* src = CB + (w + 16 * rr) * CBROW;
            #pragma unroll
            for (int g = 0; g < 2; ++g) {
                f32x4 v4 = *reinterpret_cast<const f32x4*>(src + g * 256 + lane * 4);
                #pragma unroll
                for (int q_ = 0; q_ < 4; ++q_) {
                    unsigned fu = __float_as_uint(v4[q_]);
                    u[rr][c * 8 + g * 4 + q_] =
                        (fu & 0x80000000u) ? ~fu : (fu | 0x80000000u);
                }
            }
        }
        __syncthreads();
    }

    // ---- Phase B: exact 32-bit radix top-k + softmax, 2 rows per wave ----
    #pragma unroll
    for (int rr = 0; rr < 2; ++rr) {
        unsigned cur = 0;
        for (int bit = 31; bit >= 0; --bit) {
            const unsigned cand = cur | (1u << bit);
            int cnt = 0;
            #pragma unroll
            for (int jj = 0; jj < 32; ++jj)
                cnt += __popcll(__ballot(u[rr][jj] >= cand));
            if (cnt >= KKEEP) cur = cand;
        }
        unsigned mu = 0;
        #pragma unroll
        for (int jj = 0; jj < 32; ++jj) mu = (u[rr][jj] > mu) ? u[rr][jj] : mu;
        #pragma unroll
        for (int off = 32; off; off >>= 1) {
            unsigned o = (unsigned)__shfl_xor((int)mu, off);
            mu = (o > mu) ? o : mu;
        }
        const float m = keyf(mu);
        float denom = 0.f;
        #pragma unroll
        for (int jj = 0; jj < 32; ++jj) {
            const unsigned ue = u[rr][jj];
            const float e = (ue >= cur) ? __expf(keyf(ue) - m) : 0.f;
            u[rr][jj] = __float_as_uint(e);   // overwrite key with exp value
            denom += e;
        }
        #pragma unroll
        for (int off = 32; off; off >>= 1) denom += __shfl_xor(denom, off);
        const float inv = 1.0f / denom;

        const int row = w + 16 * rr;
        float* arow = attn + ((size_t)bh * SEQ + q0 + row) * SEQ + lane * 4;
        char* Pb = smem + row * 4096;
        const int swz = (w & 7) << 4;
        #pragma unroll
        for (int c = 0; c < 4; ++c)
            #pragma unroll
            for (int g = 0; g < 2; ++g) {
                const float p0 = __uint_as_float(u[rr][c * 8 + g * 4 + 0]) * inv;
                const float p1 = __uint_as_float(u[rr][c * 8 + g * 4 + 1]) * inv;
                const float p2 = __uint_as_float(u[rr][c * 8 + g * 4 + 2]) * inv;
                const float p3 = __uint_as_float(u[rr][c * 8 + g * 4 + 3]) * inv;
                f32x4 pv = {p0, p1, p2, p3};
                __builtin_nontemporal_store(
                    pv, reinterpret_cast<f32x4*>(arow + c * 512 + g * 256));
                short4v pb;
                pb[0] = f2bf(p0); pb[1] = f2bf(p1);
                pb[2] = f2bf(p2); pb[3] = f2bf(p3);
                *reinterpret_cast<short4v*>(
                    Pb + ((c * 1024 + g * 512 + lane * 8) ^ swz)) = pb;
            }
    }
    __syncthreads();

    // ---- Phase C: ctx = P @ V; 16 waves = 4 col-groups x 4 k-quarters ----
    const int c0 = (w & 3) * 16;
    const int kq = w >> 2;
    f32x4 acc0 = {0.f, 0.f, 0.f, 0.f};   // rows 0-15
    f32x4 acc1 = {0.f, 0.f, 0.f, 0.f};   // rows 16-31
    const short* vp = vtb + ((size_t)bh * HD + c0 + r) * SEQ + kq * 512;
    const int swzr = (r & 7) << 4;
    const char* P0 = smem + r * 4096;
    const char* P1 = smem + (16 + r) * 4096;
    #pragma unroll 4
    for (int ks = 0; ks < 16; ++ks) {
        const int kk = kq * 16 + ks;
        const int off = (kk * 64 + kg * 16) ^ swzr;
        short8 vb  = ld8(vp + ks * 32 + kg * 8);
        short8 pa0 = *reinterpret_cast<const short8*>(P0 + off);
        short8 pa1 = *reinterpret_cast<const short8*>(P1 + off);
        acc0 = MFMA(pa0, vb, acc0);
        acc1 = MFMA(pa1, vb, acc1);
    }
    if (kq != 0) {
        #pragma unroll
        for (int i = 0; i < 4; ++i) {
            CT[((kq - 1) * 32 + kg * 4 + i) * 64 + c0 + r] = acc0[i];
            CT[((kq - 1) * 32 + 16 + kg * 4 + i) * 64 + c0 + r] = acc1[i];
        }
    }
    __syncthreads();
    if (kq == 0) {
        #pragma unroll
        for (int i = 0; i < 4; ++i) {
            const int rowi0 = kg * 4 + i, rowi1 = 16 + kg * 4 + i;
            float v0 = acc0[i], v1 = acc1[i];
            #pragma unroll
            for (int p_ = 0; p_ < 3; ++p_) {
                v0 += CT[(p_ * 32 + rowi0) * 64 + c0 + r];
                v1 += CT[(p_ * 32 + rowi1) * 64 + c0 + r];
            }
            ctxb[((size_t)bh * SEQ + q0 + rowi0) * HD + c0 + r] = f2bf(v0);
            ctxb[((size_t)bh * SEQ + q0 + rowi1) * HD + c0 + r] = f2bf(v1);
        }
    }
}

// ---------------- K4: out = ctx @ wo^T + bo (fp32 out) ---------------------
__global__ __launch_bounds__(256) void out_mfma(
    const short* __restrict__ ctxb, const short* __restrict__ wob,
    const float* __restrict__ bo, float* __restrict__ out)
{
    const int tid = threadIdx.x;
    const int w_  = tid >> 6, lane = tid & 63;
    const int r   = lane & 15, kg = lane >> 4;
    const int m_base = blockIdx.x * 128 + w_ * 32;
    const int n_base = blockIdx.y * 64;

    f32x4 acc[2][4] = {};

    for (int ks = 0; ks < 32; ++ks) {
        const int k0 = ks * 32 + kg * 8;
        const int h = k0 >> 6, hd = k0 & 63;
        short8 a[2];
        #pragma unroll
        for (int mf = 0; mf < 2; ++mf) {
            const int m = m_base + mf * 16 + r;
            const int b_ = m >> 11, s = m & 2047;
            a[mf] = ld8(ctxb + (((size_t)(b_ * NH + h)) * SEQ + s) * HD + hd);
        }
        #pragma unroll
        for (int nf = 0; nf < 4; ++nf) {
            short8 b = ld8(wob + (size_t)(n_base + nf * 16 + r) * DIMN + k0);
            acc[0][nf] = MFMA(a[0], b, acc[0][nf]);
            acc[1][nf] = MFMA(a[1], b, acc[1][nf]);
        }
    }

    #pragma unroll
    for (int mf = 0; mf < 2; ++mf)
        #pragma unroll
        for (int nf = 0; nf < 4; ++nf)
            #pragma unroll
            for (int i = 0; i < 4; ++i) {
                const int m  = m_base + mf * 16 + kg * 4 + i;
                const int nn = n_base + nf * 16 + r;
                out[(size_t)m * DIMN + nn] = acc[mf][nf][i] + bo[nn];
            }
}

extern "C" void kernel_launch(void* const* d_in, const int* in_sizes, int n_in,
                              void* d_out, int out_size, void* d_ws, size_t ws_size,
                              hipStream_t stream) {
    const float* x  = (const float*)d_in[0];
    const float* wq = (const float*)d_in[1];
    const float* bq = (const float*)d_in[2];
    const float* wk = (const float*)d_in[3];
    const float* bk = (const float*)d_in[4];
    const float* wv = (const float*)d_in[5];
    const float* bv = (const float*)d_in[6];
    const float* wo = (const float*)d_in[7];
    const float* bo = (const float*)d_in[8];

    float* out  = (float*)d_out;
    float* attn = out + (size_t)MROWS * DIMN;   // 512 MB region, written by fused_attn

    // --- scratch that dies before fused_attn runs: lives in the attn region ---
    short* xhi = (short*)attn;
    short* xlo = xhi + (size_t)MROWS * DIMN;
    short* wqh = xlo + (size_t)MROWS * DIMN;
    short* wql = wqh + (size_t)DIMN * DIMN;
    short* wkh = wql + (size_t)DIMN * DIMN;
    short* wkl = wkh + (size_t)DIMN * DIMN;
    short* wvb = wkl + (size_t)DIMN * DIMN;

    // --- scratch that must survive into/past fused_attn: lives in d_ws ---
    const size_t QKV = (size_t)BHN * SEQ * HD;  // 4,194,304
    short* qhi = (short*)d_ws;
    short* qlo = qhi + QKV;
    short* khi = qlo + QKV;
    short* klo = khi + QKV;
    short* vt  = klo + QKV;
    short* ctx = vt  + QKV;
    short* wob = ctx + QKV;

    conv_hilo<<<1024, 256, 0, stream>>>(x,  xhi, xlo, MROWS * DIMN);
    conv_hilo<<<512,  256, 0, stream>>>(wq, wqh, wql, DIMN * DIMN);
    conv_hilo<<<512,  256, 0, stream>>>(wk, wkh, wkl, DIMN * DIMN);
    conv_bf16<<<512,  256, 0, stream>>>(wv, wvb, DIMN * DIMN);
    conv_bf16<<<512,  256, 0, stream>>>(wo, wob, DIMN * DIMN);

    qk_mfma<<<dim3(MROWS / 128, DIMN / 64, 2), 256, 0, stream>>>(
        xhi, xlo, wqh, wql, bq, wkh, wkl, bk, qhi, qlo, khi, klo);
    v_mfma<<<dim3(MROWS / 128, DIMN / 64), 256, 0, stream>>>(
        xhi, xlo, wvb, bv, vt);

    fused_attn<<<dim3(SEQ / QROWS, BHN), 1024, 0, stream>>>(
        qhi, qlo, khi, klo, vt, attn, ctx);

    out_mfma<<<dim3(MROWS / 128, DIMN / 64), 256, 0, stream>>>(ctx, wob, bo, out);
}

// Round 8
// 785.854 us; speedup vs baseline: 1.4969x; 1.1277x over previous
//
#include <hip/hip_runtime.h>
#include <hip/hip_bf16.h>

#define DIMN 1024
#define NH 16
#define HD 64
#define SEQ 2048
#define BATCH 2
#define BHN (BATCH*NH)        // 32
#define MROWS (BATCH*SEQ)     // 4096
#define KKEEP 409
#define SCALEF 0.125f
#define QROWS 16              // q-rows per block
#define CBROW 516             // chunk-buffer row stride (floats)

typedef __attribute__((ext_vector_type(8))) short short8;
typedef __attribute__((ext_vector_type(4))) short short4v;
typedef __attribute__((ext_vector_type(4))) float f32x4;

#define MFMA(a,b,c) __builtin_amdgcn_mfma_f32_16x16x32_bf16(a,b,c,0,0,0)

static __device__ __forceinline__ short f2bf(float f) {
    __hip_bfloat16 h = __float2bfloat16(f);
    return *reinterpret_cast<short*>(&h);
}
static __device__ __forceinline__ float bf2f(short s) {
    __hip_bfloat16 h = *reinterpret_cast<__hip_bfloat16*>(&s);
    return __bfloat162float(h);
}
static __device__ __forceinline__ short8 ld8(const short* p) {
    return *reinterpret_cast<const short8*>(p);
}
// inverse of the monotone float->uint key map
static __device__ __forceinline__ float keyf(unsigned u) {
    unsigned fu = (u & 0x80000000u) ? (u ^ 0x80000000u) : ~u;
    return __uint_as_float(fu);
}

// ---------------- K0a: fp32 -> (hi, lo) bf16 pair --------------------------
__global__ void conv_hilo(const float* __restrict__ in,
                          short* __restrict__ hi, short* __restrict__ lo, int n) {
    const int n4 = n >> 2;
    for (int i = blockIdx.x * blockDim.x + threadIdx.x; i < n4;
         i += gridDim.x * blockDim.x) {
        float4 v = reinterpret_cast<const float4*>(in)[i];
        short4v h, l;
        #pragma unroll
        for (int j = 0; j < 4; ++j) {
            float f = (&v.x)[j];
            short hb = f2bf(f);
            h[j] = hb;
            l[j] = f2bf(f - bf2f(hb));
        }
        reinterpret_cast<short4v*>(hi)[i] = h;
        reinterpret_cast<short4v*>(lo)[i] = l;
    }
}

// ---------------- K0b: fp32 -> bf16 ----------------------------------------
__global__ void conv_bf16(const float* __restrict__ in, short* __restrict__ out, int n) {
    const int n4 = n >> 2;
    for (int i = blockIdx.x * blockDim.x + threadIdx.x; i < n4;
         i += gridDim.x * blockDim.x) {
        float4 v = reinterpret_cast<const float4*>(in)[i];
        short4v o;
        o[0] = f2bf(v.x); o[1] = f2bf(v.y); o[2] = f2bf(v.z); o[3] = f2bf(v.w);
        reinterpret_cast<short4v*>(out)[i] = o;
    }
}

// ---------------- K1: Q/K projection, hi/lo precision ----------------------
__global__ __launch_bounds__(256) void qk_mfma(
    const short* __restrict__ xh, const short* __restrict__ xl,
    const short* __restrict__ wqh, const short* __restrict__ wql, const float* __restrict__ bq,
    const short* __restrict__ wkh, const short* __restrict__ wkl, const float* __restrict__ bk,
    short* __restrict__ qhi, short* __restrict__ qlo,
    short* __restrict__ khi, short* __restrict__ klo)
{
    const int z = blockIdx.z;
    const short* wh = z ? wkh : wqh;
    const short* wl = z ? wkl : wql;
    const float* bias = z ? bk : bq;
    short* dhi = z ? khi : qhi;
    short* dlo = z ? klo : qlo;

    const int tid  = threadIdx.x;
    const int wv_  = tid >> 6, lane = tid & 63;
    const int r    = lane & 15, kg = lane >> 4;
    const int m_base = blockIdx.x * 128 + wv_ * 32;
    const int n_base = blockIdx.y * 64;

    f32x4 acc[2][4] = {};

    for (int ks = 0; ks < 32; ++ks) {
        const int k0 = ks * 32 + kg * 8;
        short8 ah0 = ld8(xh + (size_t)(m_base + r) * DIMN + k0);
        short8 al0 = ld8(xl + (size_t)(m_base + r) * DIMN + k0);
        short8 ah1 = ld8(xh + (size_t)(m_base + 16 + r) * DIMN + k0);
        short8 al1 = ld8(xl + (size_t)(m_base + 16 + r) * DIMN + k0);
        #pragma unroll
        for (int nf = 0; nf < 4; ++nf) {
            short8 bh = ld8(wh + (size_t)(n_base + nf * 16 + r) * DIMN + k0);
            short8 bl = ld8(wl + (size_t)(n_base + nf * 16 + r) * DIMN + k0);
            acc[0][nf] = MFMA(ah0, bh, acc[0][nf]);
            acc[0][nf] = MFMA(ah0, bl, acc[0][nf]);
            acc[0][nf] = MFMA(al0, bh, acc[0][nf]);
            acc[1][nf] = MFMA(ah1, bh, acc[1][nf]);
            acc[1][nf] = MFMA(ah1, bl, acc[1][nf]);
            acc[1][nf] = MFMA(al1, bh, acc[1][nf]);
        }
    }

    const int h = blockIdx.y;
    #pragma unroll
    for (int mf = 0; mf < 2; ++mf)
        #pragma unroll
        for (int nf = 0; nf < 4; ++nf)
            #pragma unroll
            for (int i = 0; i < 4; ++i) {
                const int m  = m_base + mf * 16 + kg * 4 + i;
                const int nn = n_base + nf * 16 + r;
                const float val = acc[mf][nf][i] + bias[nn];
                const int b_ = m >> 11, s = m & 2047;
                const size_t idx = (((size_t)(b_ * NH + h)) * SEQ + s) * HD + nf * 16 + r;
                const short hb = f2bf(val);
                dhi[idx] = hb;
                dlo[idx] = f2bf(val - bf2f(hb));
            }
}

// ---------------- K2: V projection (2-MFMA), transposed output -------------
__global__ __launch_bounds__(256) void v_mfma(
    const short* __restrict__ xh, const short* __restrict__ xl,
    const short* __restrict__ wvb, const float* __restrict__ bv,
    short* __restrict__ vt)
{
    const int tid  = threadIdx.x;
    const int wv_  = tid >> 6, lane = tid & 63;
    const int r    = lane & 15, kg = lane >> 4;
    const int m_base = blockIdx.x * 128 + wv_ * 32;
    const int n_base = blockIdx.y * 64;

    f32x4 acc[2][4] = {};

    for (int ks = 0; ks < 32; ++ks) {
        const int k0 = ks * 32 + kg * 8;
        short8 ah0 = ld8(xh + (size_t)(m_base + r) * DIMN + k0);
        short8 al0 = ld8(xl + (size_t)(m_base + r) * DIMN + k0);
        short8 ah1 = ld8(xh + (size_t)(m_base + 16 + r) * DIMN + k0);
        short8 al1 = ld8(xl + (size_t)(m_base + 16 + r) * DIMN + k0);
        #pragma unroll
        for (int nf = 0; nf < 4; ++nf) {
            short8 b = ld8(wvb + (size_t)(n_base + nf * 16 + r) * DIMN + k0);
            acc[0][nf] = MFMA(ah0, b, acc[0][nf]);
            acc[0][nf] = MFMA(al0, b, acc[0][nf]);
            acc[1][nf] = MFMA(ah1, b, acc[1][nf]);
            acc[1][nf] = MFMA(al1, b, acc[1][nf]);
        }
    }

    const int h = blockIdx.y;
    #pragma unroll
    for (int mf = 0; mf < 2; ++mf)
        #pragma unroll
        for (int nf = 0; nf < 4; ++nf)
            #pragma unroll
            for (int i = 0; i < 4; ++i) {
                const int m  = m_base + mf * 16 + kg * 4 + i;
                const int nn = n_base + nf * 16 + r;
                const float val = acc[mf][nf][i] + bv[nn];
                const int b_ = m >> 11, s = m & 2047;
                vt[(((size_t)(b_ * NH + h)) * HD + nf * 16 + r) * SEQ + s] = f2bf(val);
            }
}

// ---------------- K3: fused scores + exact top-k + softmax + PV ------------
// 512 threads = 8 waves; 16 q-rows; LDS 33 KB -> 2 blocks/CU so one block's
// VALU radix overlaps the other's MFMA/VMEM phases. Keys in registers
// (u[2][32]/wave); P written normalized per 512-col chunk into a 16 KB
// swizzled E-buffer consumed immediately by PV.
__global__ __launch_bounds__(512, 4) void fused_attn(
    const short* __restrict__ qh, const short* __restrict__ ql,
    const short* __restrict__ kh, const short* __restrict__ kl,
    const short* __restrict__ vtb, float* __restrict__ attn,
    short* __restrict__ ctxb)
{
    __shared__ __align__(16) char smem[33024];  // union: CB[16][516] | E+CT
    float* CB = (float*)smem;                   // Phase A: [16][CBROW] fp32
    // Phase C: E bf16[16][512] @ 0 (16 KB), CT fp32[16][64] @ 16384 (4 KB)
    float* CT = (float*)(smem + 16384);

    const int tid = threadIdx.x;
    const int w   = tid >> 6, lane = tid & 63;
    const int r   = lane & 15, kg = lane >> 4;
    const int bh  = blockIdx.y;
    const int q0  = blockIdx.x * QROWS;

    // ---- Phase A: S = SCALE*Q K^T in 4 chunks of 512 cols; keys -> regs ----
    const size_t qoff = ((size_t)bh * SEQ + q0 + r) * HD + kg * 8;
    short8 a0h = ld8(qh + qoff),      a0l = ld8(ql + qoff);
    short8 a1h = ld8(qh + qoff + 32), a1l = ld8(ql + qoff + 32);

    unsigned u[2][32];

    for (int c = 0; c < 4; ++c) {
        #pragma unroll
        for (int tt = 0; tt < 4; ++tt) {
            const int j0c = (w + 8 * tt) * 16;
            const size_t koff = ((size_t)bh * SEQ + c * 512 + j0c + r) * HD + kg * 8;
            short8 b0h = ld8(kh + koff),      b0l = ld8(kl + koff);
            short8 b1h = ld8(kh + koff + 32), b1l = ld8(kl + koff + 32);
            f32x4 accA = {0.f, 0.f, 0.f, 0.f};
            f32x4 accB = {0.f, 0.f, 0.f, 0.f};
            accA = MFMA(a0h, b0h, accA);
            accB = MFMA(a1h, b1h, accB);
            accA = MFMA(a0h, b0l, accA);
            accB = MFMA(a1h, b1l, accB);
            accA = MFMA(a0l, b0h, accA);
            accB = MFMA(a1l, b1h, accB);
            #pragma unroll
            for (int i = 0; i < 4; ++i)
                CB[(kg * 4 + i) * CBROW + j0c + r] = (accA[i] + accB[i]) * SCALEF;
        }
        __syncthreads();
        // pull this wave's 2 rows' 512-col slice into register keys
        #pragma unroll
        for (int rr = 0; rr < 2; ++rr) {
            const float* src = CB + (w + 8 * rr) * CBROW;
            #pragma unroll
            for (int g = 0; g < 2; ++g) {
                f32x4 v4 = *reinterpret_cast<const f32x4*>(src + g * 256 + lane * 4);
                #pragma unroll
                for (int q_ = 0; q_ < 4; ++q_) {
                    unsigned fu = __float_as_uint(v4[q_]);
                    u[rr][c * 8 + g * 4 + q_] =
                        (fu & 0x80000000u) ? ~fu : (fu | 0x80000000u);
                }
            }
        }
        __syncthreads();
    }

    // ---- Phase B-1: early-exit exact radix top-k + softmax (regs only) ----
    float inv[2];
    #pragma unroll
    for (int rr = 0; rr < 2; ++rr) {
        unsigned cur = 0;
        for (int bit = 31; bit >= 0; --bit) {
            const unsigned cand = cur | (1u << bit);
            int cnt = 0;
            #pragma unroll
            for (int jj = 0; jj < 32; ++jj)
                cnt += __popcll(__ballot(u[rr][jj] >= cand));
            if (cnt >= KKEEP) {
                cur = cand;
                if (cnt == KKEEP) break;   // kept set finalized: bit-exact
            }
        }
        unsigned mu = 0;
        #pragma unroll
        for (int jj = 0; jj < 32; ++jj) mu = (u[rr][jj] > mu) ? u[rr][jj] : mu;
        #pragma unroll
        for (int off = 32; off; off >>= 1) {
            unsigned o = (unsigned)__shfl_xor((int)mu, off);
            mu = (o > mu) ? o : mu;
        }
        const float m = keyf(mu);
        float denom = 0.f;
        #pragma unroll
        for (int jj = 0; jj < 32; ++jj) {
            const unsigned ue = u[rr][jj];
            const float e = (ue >= cur) ? __expf(keyf(ue) - m) : 0.f;
            u[rr][jj] = __float_as_uint(e);   // key -> unnormalized exp
            denom += e;
        }
        #pragma unroll
        for (int off = 32; off; off >>= 1) denom += __shfl_xor(denom, off);
        inv[rr] = 1.0f / denom;
    }

    // ---- Phase B-2 + C: per 512-col chunk: write P (attn + E-LDS), PV ----
    const int c0  = (w & 3) * 16;      // output d-col group
    const int khf = w >> 2;            // k-half within chunk (256 cols)
    const int swzw = (w & 7) << 4;     // write swizzle (row&7 == w&7)
    const int swzr = (r & 7) << 4;     // read swizzle
    f32x4 acc = {0.f, 0.f, 0.f, 0.f};

    for (int c = 0; c < 4; ++c) {
        #pragma unroll
        for (int rr = 0; rr < 2; ++rr) {
            const int row = w + 8 * rr;
            float* arow = attn + ((size_t)bh * SEQ + q0 + row) * SEQ
                        + c * 512 + lane * 4;
            char* Eb = smem + row * 1024;
            const float iv = inv[rr];
            #pragma unroll
            for (int g = 0; g < 2; ++g) {
                const float p0 = __uint_as_float(u[rr][c * 8 + g * 4 + 0]) * iv;
                const float p1 = __uint_as_float(u[rr][c * 8 + g * 4 + 1]) * iv;
                const float p2 = __uint_as_float(u[rr][c * 8 + g * 4 + 2]) * iv;
                const float p3 = __uint_as_float(u[rr][c * 8 + g * 4 + 3]) * iv;
                f32x4 pv = {p0, p1, p2, p3};
                __builtin_nontemporal_store(
                    pv, reinterpret_cast<f32x4*>(arow + g * 256));
                short4v pb;
                pb[0] = f2bf(p0); pb[1] = f2bf(p1);
                pb[2] = f2bf(p2); pb[3] = f2bf(p3);
                *reinterpret_cast<short4v*>(
                    Eb + ((g * 512 + lane * 8) ^ swzw)) = pb;
            }
        }
        __syncthreads();
        // PV over this chunk's k-half: 8 MFMA
        const short* vp = vtb + ((size_t)bh * HD + c0 + r) * SEQ
                        + c * 512 + khf * 256;
        const char* Eb2 = smem + r * 1024;
        #pragma unroll
        for (int ks = 0; ks < 8; ++ks) {
            const int kk = khf * 8 + ks;     // 32-k tile index within chunk
            short8 pa = *reinterpret_cast<const short8*>(
                Eb2 + ((kk * 64 + kg * 16) ^ swzr));
            short8 vb = ld8(vp + ks * 32 + kg * 8);
            acc = MFMA(pa, vb, acc);
        }
        __syncthreads();
    }

    // ---- CT exchange across k-halves, write ctx ----
    if (khf == 1) {
        #pragma unroll
        for (int i = 0; i < 4; ++i) CT[(kg * 4 + i) * 64 + c0 + r] = acc[i];
    }
    __syncthreads();
    if (khf == 0) {
        #pragma unroll
        for (int i = 0; i < 4; ++i) {
            const float val = acc[i] + CT[(kg * 4 + i) * 64 + c0 + r];
            ctxb[((size_t)bh * SEQ + q0 + kg * 4 + i) * HD + c0 + r] = f2bf(val);
        }
    }
}

// ---------------- K4: out = ctx @ wo^T + bo (fp32 out) ---------------------
__global__ __launch_bounds__(256) void out_mfma(
    const short* __restrict__ ctxb, const short* __restrict__ wob,
    const float* __restrict__ bo, float* __restrict__ out)
{
    const int tid = threadIdx.x;
    const int w_  = tid >> 6, lane = tid & 63;
    const int r   = lane & 15, kg = lane >> 4;
    const int m_base = blockIdx.x * 128 + w_ * 32;
    const int n_base = blockIdx.y * 64;

    f32x4 acc[2][4] = {};

    for (int ks = 0; ks < 32; ++ks) {
        const int k0 = ks * 32 + kg * 8;
        const int h = k0 >> 6, hd = k0 & 63;
        short8 a[2];
        #pragma unroll
        for (int mf = 0; mf < 2; ++mf) {
            const int m = m_base + mf * 16 + r;
            const int b_ = m >> 11, s = m & 2047;
            a[mf] = ld8(ctxb + (((size_t)(b_ * NH + h)) * SEQ + s) * HD + hd);
        }
        #pragma unroll
        for (int nf = 0; nf < 4; ++nf) {
            short8 b = ld8(wob + (size_t)(n_base + nf * 16 + r) * DIMN + k0);
            acc[0][nf] = MFMA(a[0], b, acc[0][nf]);
            acc[1][nf] = MFMA(a[1], b, acc[1][nf]);
        }
    }

    #pragma unroll
    for (int mf = 0; mf < 2; ++mf)
        #pragma unroll
        for (int nf = 0; nf < 4; ++nf)
            #pragma unroll
            for (int i = 0; i < 4; ++i) {
                const int m  = m_base + mf * 16 + kg * 4 + i;
                const int nn = n_base + nf * 16 + r;
                out[(size_t)m * DIMN + nn] = acc[mf][nf][i] + bo[nn];
            }
}

extern "C" void kernel_launch(void* const* d_in, const int* in_sizes, int n_in,
                              void* d_out, int out_size, void* d_ws, size_t ws_size,
                              hipStream_t stream) {
    const float* x  = (const float*)d_in[0];
    const float* wq = (const float*)d_in[1];
    const float* bq = (const float*)d_in[2];
    const float* wk = (const float*)d_in[3];
    const float* bk = (const float*)d_in[4];
    const float* wv = (const float*)d_in[5];
    const float* bv = (const float*)d_in[6];
    const float* wo = (const float*)d_in[7];
    const float* bo = (const float*)d_in[8];

    float* out  = (float*)d_out;
    float* attn = out + (size_t)MROWS * DIMN;   // 512 MB region, written by fused_attn

    // --- scratch that dies before fused_attn runs: lives in the attn region ---
    short* xhi = (short*)attn;
    short* xlo = xhi + (size_t)MROWS * DIMN;
    short* wqh = xlo + (size_t)MROWS * DIMN;
    short* wql = wqh + (size_t)DIMN * DIMN;
    short* wkh = wql + (size_t)DIMN * DIMN;
    short* wkl = wkh + (size_t)DIMN * DIMN;
    short* wvb = wkl + (size_t)DIMN * DIMN;

    // --- scratch that must survive into/past fused_attn: lives in d_ws ---
    const size_t QKV = (size_t)BHN * SEQ * HD;  // 4,194,304
    short* qhi = (short*)d_ws;
    short* qlo = qhi + QKV;
    short* khi = qlo + QKV;
    short* klo = khi + QKV;
    short* vt  = klo + QKV;
    short* ctx = vt  + QKV;
    short* wob = ctx + QKV;

    conv_hilo<<<1024, 256, 0, stream>>>(x,  xhi, xlo, MROWS * DIMN);
    conv_hilo<<<512,  256, 0, stream>>>(wq, wqh, wql, DIMN * DIMN);
    conv_hilo<<<512,  256, 0, stream>>>(wk, wkh, wkl, DIMN * DIMN);
    conv_bf16<<<512,  256, 0, stream>>>(wv, wvb, DIMN * DIMN);
    conv_bf16<<<512,  256, 0, stream>>>(wo, wob, DIMN * DIMN);

    qk_mfma<<<dim3(MROWS / 128, DIMN / 64, 2), 256, 0, stream>>>(
        xhi, xlo, wqh, wql, bq, wkh, wkl, bk, qhi, qlo, khi, klo);
    v_mfma<<<dim3(MROWS / 128, DIMN / 64), 256, 0, stream>>>(
        xhi, xlo, wvb, bv, vt);

    fused_attn<<<dim3(SEQ / QROWS, BHN), 512, 0, stream>>>(
        qhi, qlo, khi, klo, vt, attn, ctx);

    out_mfma<<<dim3(MROWS / 128, DIMN / 64), 256, 0, stream>>>(ctx, wob, bo, out);
}

// Round 9
// 777.237 us; speedup vs baseline: 1.5135x; 1.0111x over previous
//
#include <hip/hip_runtime.h>
#include <hip/hip_bf16.h>

#define DIMN 1024
#define NH 16
#define HD 64
#define SEQ 2048
#define BATCH 2
#define BHN (BATCH*NH)        // 32
#define MROWS (BATCH*SEQ)     // 4096
#define KKEEP 409
#define SCALEF 0.125f
#define QROWS 16              // q-rows per block

typedef __attribute__((ext_vector_type(8))) short short8;
typedef __attribute__((ext_vector_type(4))) short short4v;
typedef __attribute__((ext_vector_type(4))) float f32x4;

#define MFMA(a,b,c) __builtin_amdgcn_mfma_f32_16x16x32_bf16(a,b,c,0,0,0)

static __device__ __forceinline__ short f2bf(float f) {
    __hip_bfloat16 h = __float2bfloat16(f);
    return *reinterpret_cast<short*>(&h);
}
static __device__ __forceinline__ float bf2f(short s) {
    __hip_bfloat16 h = *reinterpret_cast<__hip_bfloat16*>(&s);
    return __bfloat162float(h);
}
static __device__ __forceinline__ short8 ld8(const short* p) {
    return *reinterpret_cast<const short8*>(p);
}
// inverse of the monotone float->uint key map
static __device__ __forceinline__ float keyf(unsigned u) {
    unsigned fu = (u & 0x80000000u) ? (u ^ 0x80000000u) : ~u;
    return __uint_as_float(fu);
}

// ---------------- K0a: fp32 -> (hi, lo) bf16 pair --------------------------
__global__ void conv_hilo(const float* __restrict__ in,
                          short* __restrict__ hi, short* __restrict__ lo, int n) {
    const int n4 = n >> 2;
    for (int i = blockIdx.x * blockDim.x + threadIdx.x; i < n4;
         i += gridDim.x * blockDim.x) {
        float4 v = reinterpret_cast<const float4*>(in)[i];
        short4v h, l;
        #pragma unroll
        for (int j = 0; j < 4; ++j) {
            float f = (&v.x)[j];
            short hb = f2bf(f);
            h[j] = hb;
            l[j] = f2bf(f - bf2f(hb));
        }
        reinterpret_cast<short4v*>(hi)[i] = h;
        reinterpret_cast<short4v*>(lo)[i] = l;
    }
}

// ---------------- K0b: fp32 -> bf16 ----------------------------------------
__global__ void conv_bf16(const float* __restrict__ in, short* __restrict__ out, int n) {
    const int n4 = n >> 2;
    for (int i = blockIdx.x * blockDim.x + threadIdx.x; i < n4;
         i += gridDim.x * blockDim.x) {
        float4 v = reinterpret_cast<const float4*>(in)[i];
        short4v o;
        o[0] = f2bf(v.x); o[1] = f2bf(v.y); o[2] = f2bf(v.z); o[3] = f2bf(v.w);
        reinterpret_cast<short4v*>(out)[i] = o;
    }
}

// ---------------- K1: Q/K projection, hi/lo precision ----------------------
__global__ __launch_bounds__(256) void qk_mfma(
    const short* __restrict__ xh, const short* __restrict__ xl,
    const short* __restrict__ wqh, const short* __restrict__ wql, const float* __restrict__ bq,
    const short* __restrict__ wkh, const short* __restrict__ wkl, const float* __restrict__ bk,
    short* __restrict__ qhi, short* __restrict__ qlo,
    short* __restrict__ khi, short* __restrict__ klo)
{
    const int z = blockIdx.z;
    const short* wh = z ? wkh : wqh;
    const short* wl = z ? wkl : wql;
    const float* bias = z ? bk : bq;
    short* dhi = z ? khi : qhi;
    short* dlo = z ? klo : qlo;

    const int tid  = threadIdx.x;
    const int wv_  = tid >> 6, lane = tid & 63;
    const int r    = lane & 15, kg = lane >> 4;
    const int m_base = blockIdx.x * 128 + wv_ * 32;
    const int n_base = blockIdx.y * 64;

    f32x4 acc[2][4] = {};

    for (int ks = 0; ks < 32; ++ks) {
        const int k0 = ks * 32 + kg * 8;
        short8 ah0 = ld8(xh + (size_t)(m_base + r) * DIMN + k0);
        short8 al0 = ld8(xl + (size_t)(m_base + r) * DIMN + k0);
        short8 ah1 = ld8(xh + (size_t)(m_base + 16 + r) * DIMN + k0);
        short8 al1 = ld8(xl + (size_t)(m_base + 16 + r) * DIMN + k0);
        #pragma unroll
        for (int nf = 0; nf < 4; ++nf) {
            short8 bh = ld8(wh + (size_t)(n_base + nf * 16 + r) * DIMN + k0);
            short8 bl = ld8(wl + (size_t)(n_base + nf * 16 + r) * DIMN + k0);
            acc[0][nf] = MFMA(ah0, bh, acc[0][nf]);
            acc[0][nf] = MFMA(ah0, bl, acc[0][nf]);
            acc[0][nf] = MFMA(al0, bh, acc[0][nf]);
            acc[1][nf] = MFMA(ah1, bh, acc[1][nf]);
            acc[1][nf] = MFMA(ah1, bl, acc[1][nf]);
            acc[1][nf] = MFMA(al1, bh, acc[1][nf]);
        }
    }

    const int h = blockIdx.y;
    #pragma unroll
    for (int mf = 0; mf < 2; ++mf)
        #pragma unroll
        for (int nf = 0; nf < 4; ++nf)
            #pragma unroll
            for (int i = 0; i < 4; ++i) {
                const int m  = m_base + mf * 16 + kg * 4 + i;
                const int nn = n_base + nf * 16 + r;
                const float val = acc[mf][nf][i] + bias[nn];
                const int b_ = m >> 11, s = m & 2047;
                const size_t idx = (((size_t)(b_ * NH + h)) * SEQ + s) * HD + nf * 16 + r;
                const short hb = f2bf(val);
                dhi[idx] = hb;
                dlo[idx] = f2bf(val - bf2f(hb));
            }
}

// ---------------- K2: V projection (2-MFMA), transposed output -------------
__global__ __launch_bounds__(256) void v_mfma(
    const short* __restrict__ xh, const short* __restrict__ xl,
    const short* __restrict__ wvb, const float* __restrict__ bv,
    short* __restrict__ vt)
{
    const int tid  = threadIdx.x;
    const int wv_  = tid >> 6, lane = tid & 63;
    const int r    = lane & 15, kg = lane >> 4;
    const int m_base = blockIdx.x * 128 + wv_ * 32;
    const int n_base = blockIdx.y * 64;

    f32x4 acc[2][4] = {};

    for (int ks = 0; ks < 32; ++ks) {
        const int k0 = ks * 32 + kg * 8;
        short8 ah0 = ld8(xh + (size_t)(m_base + r) * DIMN + k0);
        short8 al0 = ld8(xl + (size_t)(m_base + r) * DIMN + k0);
        short8 ah1 = ld8(xh + (size_t)(m_base + 16 + r) * DIMN + k0);
        short8 al1 = ld8(xl + (size_t)(m_base + 16 + r) * DIMN + k0);
        #pragma unroll
        for (int nf = 0; nf < 4; ++nf) {
            short8 b = ld8(wvb + (size_t)(n_base + nf * 16 + r) * DIMN + k0);
            acc[0][nf] = MFMA(ah0, b, acc[0][nf]);
            acc[0][nf] = MFMA(al0, b, acc[0][nf]);
            acc[1][nf] = MFMA(ah1, b, acc[1][nf]);
            acc[1][nf] = MFMA(al1, b, acc[1][nf]);
        }
    }

    const int h = blockIdx.y;
    #pragma unroll
    for (int mf = 0; mf < 2; ++mf)
        #pragma unroll
        for (int nf = 0; nf < 4; ++nf)
            #pragma unroll
            for (int i = 0; i < 4; ++i) {
                const int m  = m_base + mf * 16 + kg * 4 + i;
                const int nn = n_base + nf * 16 + r;
                const float val = acc[mf][nf][i] + bv[nn];
                const int b_ = m >> 11, s = m & 2047;
                vt[(((size_t)(b_ * NH + h)) * HD + nf * 16 + r) * SEQ + s] = f2bf(val);
            }
}

// ---------------- K3: fused scores + exact top-k + softmax + PV ------------
// 512 threads = 8 waves; 16 q-rows; LDS 32 KB. Software-pipelined:
// Phase A: 8x 256-col chunks, CB double-buffered (2x16KB) -> STAGE(c+1)
// overlaps PULL(c), one barrier per chunk. Phase C: E double-buffered
// (2x8KB) -> PWRITE(c+1) overlaps PV(c). Occupancy is register-ceiling
// limited (u[2][32] keys ~ 124 unified regs -> 4 waves/SIMD), so this
// attacks the per-block critical path instead.
__global__ __launch_bounds__(512, 4) void fused_attn(
    const short* __restrict__ qh, const short* __restrict__ ql,
    const short* __restrict__ kh, const short* __restrict__ kl,
    const short* __restrict__ vtb, float* __restrict__ attn,
    short* __restrict__ ctxb)
{
    __shared__ __align__(16) char smem[32768];
    // Phase A: CB0 fp32[16][256] @0, CB1 @16384
    // Phase C: E0 bf16[16][256] @0 (8KB), E1 @8192, CT fp32[16][64] @16384
    float* CT = (float*)(smem + 16384);

    const int tid = threadIdx.x;
    const int w   = tid >> 6, lane = tid & 63;
    const int r   = lane & 15, kg = lane >> 4;
    const int bh  = blockIdx.y;
    const int q0  = blockIdx.x * QROWS;

    // ---- Phase A: S = SCALE*Q K^T, 8 chunks of 256 cols, pipelined ----
    const size_t qoff = ((size_t)bh * SEQ + q0 + r) * HD + kg * 8;
    short8 a0h = ld8(qh + qoff),      a0l = ld8(ql + qoff);
    short8 a1h = ld8(qh + qoff + 32), a1l = ld8(ql + qoff + 32);

    unsigned u[2][32];

    auto STAGE = [&](int c, float* buf) {
        #pragma unroll
        for (int tt = 0; tt < 2; ++tt) {
            const int j0c = (w + 8 * tt) * 16;
            const size_t koff = ((size_t)bh * SEQ + c * 256 + j0c + r) * HD + kg * 8;
            short8 b0h = ld8(kh + koff),      b0l = ld8(kl + koff);
            short8 b1h = ld8(kh + koff + 32), b1l = ld8(kl + koff + 32);
            f32x4 accA = {0.f, 0.f, 0.f, 0.f};
            f32x4 accB = {0.f, 0.f, 0.f, 0.f};
            accA = MFMA(a0h, b0h, accA);
            accB = MFMA(a1h, b1h, accB);
            accA = MFMA(a0h, b0l, accA);
            accB = MFMA(a1h, b1l, accB);
            accA = MFMA(a0l, b0h, accA);
            accB = MFMA(a1l, b1h, accB);
            #pragma unroll
            for (int i = 0; i < 4; ++i)
                buf[(kg * 4 + i) * 256 + j0c + r] = (accA[i] + accB[i]) * SCALEF;
        }
    };

    STAGE(0, (float*)smem);
    __syncthreads();
    #pragma unroll
    for (int c = 0; c < 8; ++c) {
        float* cur = (float*)(smem + ((c & 1) ? 16384 : 0));
        float* nxt = (float*)(smem + ((c & 1) ? 0 : 16384));
        if (c + 1 < 8) STAGE(c + 1, nxt);     // overlaps PULL below
        #pragma unroll
        for (int rr = 0; rr < 2; ++rr) {
            const float* src = cur + (w + 8 * rr) * 256;
            f32x4 v4 = *reinterpret_cast<const f32x4*>(src + lane * 4);
            #pragma unroll
            for (int q_ = 0; q_ < 4; ++q_) {
                unsigned fu = __float_as_uint(v4[q_]);
                u[rr][c * 4 + q_] = (fu & 0x80000000u) ? ~fu : (fu | 0x80000000u);
            }
        }
        __syncthreads();
    }

    // ---- Phase B-1: early-exit exact radix top-k + softmax (regs only) ----
    float inv[2];
    #pragma unroll
    for (int rr = 0; rr < 2; ++rr) {
        unsigned cur = 0;
        for (int bit = 31; bit >= 0; --bit) {
            const unsigned cand = cur | (1u << bit);
            int cnt = 0;
            #pragma unroll
            for (int jj = 0; jj < 32; ++jj)
                cnt += __popcll(__ballot(u[rr][jj] >= cand));
            if (cnt >= KKEEP) {
                cur = cand;
                if (cnt == KKEEP) break;   // kept set finalized: bit-exact
            }
        }
        unsigned mu = 0;
        #pragma unroll
        for (int jj = 0; jj < 32; ++jj) mu = (u[rr][jj] > mu) ? u[rr][jj] : mu;
        #pragma unroll
        for (int off = 32; off; off >>= 1) {
            unsigned o = (unsigned)__shfl_xor((int)mu, off);
            mu = (o > mu) ? o : mu;
        }
        const float m = keyf(mu);
        float denom = 0.f;
        #pragma unroll
        for (int jj = 0; jj < 32; ++jj) {
            const unsigned ue = u[rr][jj];
            const float e = (ue >= cur) ? __expf(keyf(ue) - m) : 0.f;
            u[rr][jj] = __float_as_uint(e);   // key -> unnormalized exp
            denom += e;
        }
        #pragma unroll
        for (int off = 32; off; off >>= 1) denom += __shfl_xor(denom, off);
        inv[rr] = 1.0f / denom;
    }

    // ---- Phase B-2 + C: 8x 256-col chunks, E double-buffered, pipelined ----
    const int c0  = (w & 3) * 16;      // output d-col group
    const int khf = w >> 2;            // k-half within chunk (128 cols)
    const int swzw = (w & 7) << 4;     // write swizzle ((row&7)<<4 for both rows)
    const int swzr = (r & 7) << 4;     // read swizzle
    f32x4 acc = {0.f, 0.f, 0.f, 0.f};

    auto PWRITE = [&](int c, char* Ebase) {
        #pragma unroll
        for (int rr = 0; rr < 2; ++rr) {
            const int row = w + 8 * rr;
            const float iv = inv[rr];
            const float p0 = __uint_as_float(u[rr][c * 4 + 0]) * iv;
            const float p1 = __uint_as_float(u[rr][c * 4 + 1]) * iv;
            const float p2 = __uint_as_float(u[rr][c * 4 + 2]) * iv;
            const float p3 = __uint_as_float(u[rr][c * 4 + 3]) * iv;
            f32x4 pv = {p0, p1, p2, p3};
            __builtin_nontemporal_store(pv, reinterpret_cast<f32x4*>(
                attn + ((size_t)bh * SEQ + q0 + row) * SEQ + c * 256 + lane * 4));
            short4v pb;
            pb[0] = f2bf(p0); pb[1] = f2bf(p1);
            pb[2] = f2bf(p2); pb[3] = f2bf(p3);
            *reinterpret_cast<short4v*>(
                Ebase + row * 512 + ((lane * 8) ^ swzw)) = pb;
        }
    };
    auto PVSTEP = [&](int c, const char* Ebase) {
        const short* vp = vtb + ((size_t)bh * HD + c0 + r) * SEQ
                        + c * 256 + khf * 128;
        const char* Eb2 = Ebase + r * 512;
        #pragma unroll
        for (int ks = 0; ks < 4; ++ks) {
            const int kk = khf * 4 + ks;
            short8 pa = *reinterpret_cast<const short8*>(
                Eb2 + ((kk * 64 + kg * 16) ^ swzr));
            short8 vb = ld8(vp + ks * 32 + kg * 8);
            acc = MFMA(pa, vb, acc);
        }
    };

    PWRITE(0, smem);
    __syncthreads();
    #pragma unroll
    for (int c = 0; c < 8; ++c) {
        char* curE = smem + ((c & 1) ? 8192 : 0);
        char* nxtE = smem + ((c & 1) ? 0 : 8192);
        if (c + 1 < 8) PWRITE(c + 1, nxtE);   // overlaps PV below
        PVSTEP(c, curE);
        __syncthreads();
    }

    // ---- CT exchange across k-halves, write ctx ----
    if (khf == 1) {
        #pragma unroll
        for (int i = 0; i < 4; ++i) CT[(kg * 4 + i) * 64 + c0 + r] = acc[i];
    }
    __syncthreads();
    if (khf == 0) {
        #pragma unroll
        for (int i = 0; i < 4; ++i) {
            const float val = acc[i] + CT[(kg * 4 + i) * 64 + c0 + r];
            ctxb[((size_t)bh * SEQ + q0 + kg * 4 + i) * HD + c0 + r] = f2bf(val);
        }
    }
}

// ---------------- K4: out = ctx @ wo^T + bo (fp32 out) ---------------------
__global__ __launch_bounds__(256) void out_mfma(
    const short* __restrict__ ctxb, const short* __restrict__ wob,
    const float* __restrict__ bo, float* __restrict__ out)
{
    const int tid = threadIdx.x;
    const int w_  = tid >> 6, lane = tid & 63;
    const int r   = lane & 15, kg = lane >> 4;
    const int m_base = blockIdx.x * 128 + w_ * 32;
    const int n_base = blockIdx.y * 64;

    f32x4 acc[2][4] = {};

    for (int ks = 0; ks < 32; ++ks) {
        const int k0 = ks * 32 + kg * 8;
        const int h = k0 >> 6, hd = k0 & 63;
        short8 a[2];
        #pragma unroll
        for (int mf = 0; mf < 2; ++mf) {
            const int m = m_base + mf * 16 + r;
            const int b_ = m >> 11, s = m & 2047;
            a[mf] = ld8(ctxb + (((size_t)(b_ * NH + h)) * SEQ + s) * HD + hd);
        }
        #pragma unroll
        for (int nf = 0; nf < 4; ++nf) {
            short8 b = ld8(wob + (size_t)(n_base + nf * 16 + r) * DIMN + k0);
            acc[0][nf] = MFMA(a[0], b, acc[0][nf]);
            acc[1][nf] = MFMA(a[1], b, acc[1][nf]);
        }
    }

    #pragma unroll
    for (int mf = 0; mf < 2; ++mf)
        #pragma unroll
        for (int nf = 0; nf < 4; ++nf)
            #pragma unroll
            for (int i = 0; i < 4; ++i) {
                const int m  = m_base + mf * 16 + kg * 4 + i;
                const int nn = n_base + nf * 16 + r;
                out[(size_t)m * DIMN + nn] = acc[mf][nf][i] + bo[nn];
            }
}

extern "C" void kernel_launch(void* const* d_in, const int* in_sizes, int n_in,
                              void* d_out, int out_size, void* d_ws, size_t ws_size,
                              hipStream_t stream) {
    const float* x  = (const float*)d_in[0];
    const float* wq = (const float*)d_in[1];
    const float* bq = (const float*)d_in[2];
    const float* wk = (const float*)d_in[3];
    const float* bk = (const float*)d_in[4];
    const float* wv = (const float*)d_in[5];
    const float* bv = (const float*)d_in[6];
    const float* wo = (const float*)d_in[7];
    const float* bo = (const float*)d_in[8];

    float* out  = (float*)d_out;
    float* attn = out + (size_t)MROWS * DIMN;   // 512 MB region, written by fused_attn

    // --- scratch that dies before fused_attn runs: lives in the attn region ---
    short* xhi = (short*)attn;
    short* xlo = xhi + (size_t)MROWS * DIMN;
    short* wqh = xlo + (size_t)MROWS * DIMN;
    short* wql = wqh + (size_t)DIMN * DIMN;
    short* wkh = wql + (size_t)DIMN * DIMN;
    short* wkl = wkh + (size_t)DIMN * DIMN;
    short* wvb = wkl + (size_t)DIMN * DIMN;

    // --- scratch that must survive into/past fused_attn: lives in d_ws ---
    const size_t QKV = (size_t)BHN * SEQ * HD;  // 4,194,304
    short* qhi = (short*)d_ws;
    short* qlo = qhi + QKV;
    short* khi = qlo + QKV;
    short* klo = khi + QKV;
    short* vt  = klo + QKV;
    short* ctx = vt  + QKV;
    short* wob = ctx + QKV;

    conv_hilo<<<1024, 256, 0, stream>>>(x,  xhi, xlo, MROWS * DIMN);
    conv_hilo<<<512,  256, 0, stream>>>(wq, wqh, wql, DIMN * DIMN);
    conv_hilo<<<512,  256, 0, stream>>>(wk, wkh, wkl, DIMN * DIMN);
    conv_bf16<<<512,  256, 0, stream>>>(wv, wvb, DIMN * DIMN);
    conv_bf16<<<512,  256, 0, stream>>>(wo, wob, DIMN * DIMN);

    qk_mfma<<<dim3(MROWS / 128, DIMN / 64, 2), 256, 0, stream>>>(
        xhi, xlo, wqh, wql, bq, wkh, wkl, bk, qhi, qlo, khi, klo);
    v_mfma<<<dim3(MROWS / 128, DIMN / 64), 256, 0, stream>>>(
        xhi, xlo, wvb, bv, vt);

    fused_attn<<<dim3(SEQ / QROWS, BHN), 512, 0, stream>>>(
        qhi, qlo, khi, klo, vt, attn, ctx);

    out_mfma<<<dim3(MROWS / 128, DIMN / 64), 256, 0, stream>>>(ctx, wob, bo, out);
}

// Round 11
// 775.974 us; speedup vs baseline: 1.5159x; 1.0016x over previous
//
#include <hip/hip_runtime.h>
#include <hip/hip_bf16.h>

#define DIMN 1024
#define NH 16
#define HD 64
#define SEQ 2048
#define BATCH 2
#define BHN (BATCH*NH)        // 32
#define MROWS (BATCH*SEQ)     // 4096
#define KKEEP 409
#define SCALEF 0.125f
#define QROWS 16              // q-rows per block

typedef __attribute__((ext_vector_type(8))) short short8;
typedef __attribute__((ext_vector_type(4))) short short4v;
typedef __attribute__((ext_vector_type(4))) float f32x4;

#define MFMA(a,b,c) __builtin_amdgcn_mfma_f32_16x16x32_bf16(a,b,c,0,0,0)

static __device__ __forceinline__ short f2bf(float f) {
    __hip_bfloat16 h = __float2bfloat16(f);
    return *reinterpret_cast<short*>(&h);
}
static __device__ __forceinline__ float bf2f(short s) {
    __hip_bfloat16 h = *reinterpret_cast<__hip_bfloat16*>(&s);
    return __bfloat162float(h);
}
static __device__ __forceinline__ short8 ld8(const short* p) {
    return *reinterpret_cast<const short8*>(p);
}
// inverse of the monotone float->uint key map
static __device__ __forceinline__ float keyf(unsigned u) {
    unsigned fu = (u & 0x80000000u) ? (u ^ 0x80000000u) : ~u;
    return __uint_as_float(fu);
}

// ---------------- K0a: fp32 -> (hi, lo) bf16 pair --------------------------
__global__ void conv_hilo(const float* __restrict__ in,
                          short* __restrict__ hi, short* __restrict__ lo, int n) {
    const int n4 = n >> 2;
    for (int i = blockIdx.x * blockDim.x + threadIdx.x; i < n4;
         i += gridDim.x * blockDim.x) {
        float4 v = reinterpret_cast<const float4*>(in)[i];
        short4v h, l;
        #pragma unroll
        for (int j = 0; j < 4; ++j) {
            float f = (&v.x)[j];
            short hb = f2bf(f);
            h[j] = hb;
            l[j] = f2bf(f - bf2f(hb));
        }
        reinterpret_cast<short4v*>(hi)[i] = h;
        reinterpret_cast<short4v*>(lo)[i] = l;
    }
}

// ---------------- K0b: fp32 -> bf16 ----------------------------------------
__global__ void conv_bf16(const float* __restrict__ in, short* __restrict__ out, int n) {
    const int n4 = n >> 2;
    for (int i = blockIdx.x * blockDim.x + threadIdx.x; i < n4;
         i += gridDim.x * blockDim.x) {
        float4 v = reinterpret_cast<const float4*>(in)[i];
        short4v o;
        o[0] = f2bf(v.x); o[1] = f2bf(v.y); o[2] = f2bf(v.z); o[3] = f2bf(v.w);
        reinterpret_cast<short4v*>(out)[i] = o;
    }
}

// ---------------- K1: Q/K projection, hi/lo precision ----------------------
__global__ __launch_bounds__(256) void qk_mfma(
    const short* __restrict__ xh, const short* __restrict__ xl,
    const short* __restrict__ wqh, const short* __restrict__ wql, const float* __restrict__ bq,
    const short* __restrict__ wkh, const short* __restrict__ wkl, const float* __restrict__ bk,
    short* __restrict__ qhi, short* __restrict__ qlo,
    short* __restrict__ khi, short* __restrict__ klo)
{
    const int z = blockIdx.z;
    const short* wh = z ? wkh : wqh;
    const short* wl = z ? wkl : wql;
    const float* bias = z ? bk : bq;
    short* dhi = z ? khi : qhi;
    short* dlo = z ? klo : qlo;

    const int tid  = threadIdx.x;
    const int wv_  = tid >> 6, lane = tid & 63;
    const int r    = lane & 15, kg = lane >> 4;
    const int m_base = blockIdx.x * 128 + wv_ * 32;
    const int n_base = blockIdx.y * 64;

    f32x4 acc[2][4] = {};

    for (int ks = 0; ks < 32; ++ks) {
        const int k0 = ks * 32 + kg * 8;
        short8 ah0 = ld8(xh + (size_t)(m_base + r) * DIMN + k0);
        short8 al0 = ld8(xl + (size_t)(m_base + r) * DIMN + k0);
        short8 ah1 = ld8(xh + (size_t)(m_base + 16 + r) * DIMN + k0);
        short8 al1 = ld8(xl + (size_t)(m_base + 16 + r) * DIMN + k0);
        #pragma unroll
        for (int nf = 0; nf < 4; ++nf) {
            short8 bh = ld8(wh + (size_t)(n_base + nf * 16 + r) * DIMN + k0);
            short8 bl = ld8(wl + (size_t)(n_base + nf * 16 + r) * DIMN + k0);
            acc[0][nf] = MFMA(ah0, bh, acc[0][nf]);
            acc[0][nf] = MFMA(ah0, bl, acc[0][nf]);
            acc[0][nf] = MFMA(al0, bh, acc[0][nf]);
            acc[1][nf] = MFMA(ah1, bh, acc[1][nf]);
            acc[1][nf] = MFMA(ah1, bl, acc[1][nf]);
            acc[1][nf] = MFMA(al1, bh, acc[1][nf]);
        }
    }

    const int h = blockIdx.y;
    #pragma unroll
    for (int mf = 0; mf < 2; ++mf)
        #pragma unroll
        for (int nf = 0; nf < 4; ++nf)
            #pragma unroll
            for (int i = 0; i < 4; ++i) {
                const int m  = m_base + mf * 16 + kg * 4 + i;
                const int nn = n_base + nf * 16 + r;
                const float val = acc[mf][nf][i] + bias[nn];
                const int b_ = m >> 11, s = m & 2047;
                const size_t idx = (((size_t)(b_ * NH + h)) * SEQ + s) * HD + nf * 16 + r;
                const short hb = f2bf(val);
                dhi[idx] = hb;
                dlo[idx] = f2bf(val - bf2f(hb));
            }
}

// ---------------- K2: V projection (2-MFMA), transposed output -------------
__global__ __launch_bounds__(256) void v_mfma(
    const short* __restrict__ xh, const short* __restrict__ xl,
    const short* __restrict__ wvb, const float* __restrict__ bv,
    short* __restrict__ vt)
{
    const int tid  = threadIdx.x;
    const int wv_  = tid >> 6, lane = tid & 63;
    const int r    = lane & 15, kg = lane >> 4;
    const int m_base = blockIdx.x * 128 + wv_ * 32;
    const int n_base = blockIdx.y * 64;

    f32x4 acc[2][4] = {};

    for (int ks = 0; ks < 32; ++ks) {
        const int k0 = ks * 32 + kg * 8;
        short8 ah0 = ld8(xh + (size_t)(m_base + r) * DIMN + k0);
        short8 al0 = ld8(xl + (size_t)(m_base + r) * DIMN + k0);
        short8 ah1 = ld8(xh + (size_t)(m_base + 16 + r) * DIMN + k0);
        short8 al1 = ld8(xl + (size_t)(m_base + 16 + r) * DIMN + k0);
        #pragma unroll
        for (int nf = 0; nf < 4; ++nf) {
            short8 b = ld8(wvb + (size_t)(n_base + nf * 16 + r) * DIMN + k0);
            acc[0][nf] = MFMA(ah0, b, acc[0][nf]);
            acc[0][nf] = MFMA(al0, b, acc[0][nf]);
            acc[1][nf] = MFMA(ah1, b, acc[1][nf]);
            acc[1][nf] = MFMA(al1, b, acc[1][nf]);
        }
    }

    const int h = blockIdx.y;
    #pragma unroll
    for (int mf = 0; mf < 2; ++mf)
        #pragma unroll
        for (int nf = 0; nf < 4; ++nf)
            #pragma unroll
            for (int i = 0; i < 4; ++i) {
                const int m  = m_base + mf * 16 + kg * 4 + i;
                const int nn = n_base + nf * 16 + r;
                const float val = acc[mf][nf][i] + bv[nn];
                const int b_ = m >> 11, s = m & 2047;
                vt[(((size_t)(b_ * NH + h)) * HD + nf * 16 + r) * SEQ + s] = f2bf(val);
            }
}

// ---------------- K3: fused scores + exact top-k + softmax + PV ------------
// 512 threads = 8 waves; 16 q-rows; LDS 32 KB; 2 blocks/CU.
// KEY CHANGE vs R9: no global attn stores inside the barrier region. Every
// __syncthreads compiles to s_waitcnt vmcnt(0)+s_barrier, which drains
// outstanding HBM stores; interleaving the 537 MB attn stream with per-chunk
// barriers serialized the kernel on store-drain latency. Now the chunk loop
// writes only LDS (E) and the full attn stream is emitted AFTER the final
// barrier, fire-and-forget.
__global__ __launch_bounds__(512, 4) void fused_attn(
    const short* __restrict__ qh, const short* __restrict__ ql,
    const short* __restrict__ kh, const short* __restrict__ kl,
    const short* __restrict__ vtb, float* __restrict__ attn,
    short* __restrict__ ctxb)
{
    __shared__ __align__(16) char smem[32768];
    // Phase A: CB0 fp32[16][256] @0, CB1 @16384
    // Phase C: E0 bf16[16][256] @0 (8KB), E1 @8192, CT fp32[16][64] @16384
    float* CT = (float*)(smem + 16384);

    const int tid = threadIdx.x;
    const int w   = tid >> 6, lane = tid & 63;
    const int r   = lane & 15, kg = lane >> 4;
    const int bh  = blockIdx.y;
    const int q0  = blockIdx.x * QROWS;

    // ---- Phase A: S = SCALE*Q K^T, 8 chunks of 256 cols, pipelined ----
    const size_t qoff = ((size_t)bh * SEQ + q0 + r) * HD + kg * 8;
    short8 a0h = ld8(qh + qoff),      a0l = ld8(ql + qoff);
    short8 a1h = ld8(qh + qoff + 32), a1l = ld8(ql + qoff + 32);

    unsigned u[2][32];

    auto STAGE = [&](int c, float* buf) {
        #pragma unroll
        for (int tt = 0; tt < 2; ++tt) {
            const int j0c = (w + 8 * tt) * 16;
            const size_t koff = ((size_t)bh * SEQ + c * 256 + j0c + r) * HD + kg * 8;
            short8 b0h = ld8(kh + koff);
            short8 b0l = ld8(kl + koff);
            short8 b1h = ld8(kh + koff + 32);
            short8 b1l = ld8(kl + koff + 32);
            f32x4 accA = {0.f, 0.f, 0.f, 0.f};
            f32x4 accB = {0.f, 0.f, 0.f, 0.f};
            accA = MFMA(a0h, b0h, accA);
            accB = MFMA(a1h, b1h, accB);
            accA = MFMA(a0h, b0l, accA);
            accB = MFMA(a1h, b1l, accB);
            accA = MFMA(a0l, b0h, accA);
            accB = MFMA(a1l, b1h, accB);
            #pragma unroll
            for (int i = 0; i < 4; ++i)
                buf[(kg * 4 + i) * 256 + j0c + r] = (accA[i] + accB[i]) * SCALEF;
        }
    };

    STAGE(0, (float*)smem);
    __syncthreads();
    #pragma unroll
    for (int c = 0; c < 8; ++c) {
        float* cur = (float*)(smem + ((c & 1) ? 16384 : 0));
        float* nxt = (float*)(smem + ((c & 1) ? 0 : 16384));
        if (c + 1 < 8) STAGE(c + 1, nxt);     // overlaps PULL below
        #pragma unroll
        for (int rr = 0; rr < 2; ++rr) {
            const float* src = cur + (w + 8 * rr) * 256;
            f32x4 v4 = *reinterpret_cast<const f32x4*>(src + lane * 4);
            #pragma unroll
            for (int q_ = 0; q_ < 4; ++q_) {
                unsigned fu = __float_as_uint(v4[q_]);
                u[rr][c * 4 + q_] = (fu & 0x80000000u) ? ~fu : (fu | 0x80000000u);
            }
        }
        __syncthreads();
    }

    // ---- Phase B-1: early-exit exact radix top-k + softmax (regs only) ----
    float inv[2];
    #pragma unroll
    for (int rr = 0; rr < 2; ++rr) {
        unsigned cur = 0;
        for (int bit = 31; bit >= 0; --bit) {
            const unsigned cand = cur | (1u << bit);
            int cnt = 0;
            #pragma unroll
            for (int jj = 0; jj < 32; ++jj)
                cnt += __popcll(__ballot(u[rr][jj] >= cand));
            if (cnt >= KKEEP) {
                cur = cand;
                if (cnt == KKEEP) break;   // kept set finalized: bit-exact
            }
        }
        unsigned mu = 0;
        #pragma unroll
        for (int jj = 0; jj < 32; ++jj) mu = (u[rr][jj] > mu) ? u[rr][jj] : mu;
        #pragma unroll
        for (int off = 32; off; off >>= 1) {
            unsigned o = (unsigned)__shfl_xor((int)mu, off);
            mu = (o > mu) ? o : mu;
        }
        const float m = keyf(mu);
        float denom = 0.f;
        #pragma unroll
        for (int jj = 0; jj < 32; ++jj) {
            const unsigned ue = u[rr][jj];
            const float e = (ue >= cur) ? __expf(keyf(ue) - m) : 0.f;
            u[rr][jj] = __float_as_uint(e);   // key -> unnormalized exp
            denom += e;
        }
        #pragma unroll
        for (int off = 32; off; off >>= 1) denom += __shfl_xor(denom, off);
        inv[rr] = 1.0f / denom;
    }

    // ---- Phase C: 8x 256-col chunks; E double-buffered; LDS writes only ----
    const int c0  = (w & 3) * 16;      // output d-col group
    const int khf = w >> 2;            // k-half within chunk (128 cols)
    const int swzw = (w & 7) << 4;     // write swizzle ((row&7)<<4 for both rows)
    const int swzr = (r & 7) << 4;     // read swizzle
    f32x4 acc = {0.f, 0.f, 0.f, 0.f};

    auto EWRITE = [&](int c, char* Ebase) {
        #pragma unroll
        for (int rr = 0; rr < 2; ++rr) {
            const int row = w + 8 * rr;
            const float iv = inv[rr];
            short4v pb;
            pb[0] = f2bf(__uint_as_float(u[rr][c * 4 + 0]) * iv);
            pb[1] = f2bf(__uint_as_float(u[rr][c * 4 + 1]) * iv);
            pb[2] = f2bf(__uint_as_float(u[rr][c * 4 + 2]) * iv);
            pb[3] = f2bf(__uint_as_float(u[rr][c * 4 + 3]) * iv);
            *reinterpret_cast<short4v*>(
                Ebase + row * 512 + ((lane * 8) ^ swzw)) = pb;
        }
    };
    auto PVSTEP = [&](int c, const char* Ebase) {
        const short* vp = vtb + ((size_t)bh * HD + c0 + r) * SEQ
                        + c * 256 + khf * 128;
        const char* Eb2 = Ebase + r * 512;
        #pragma unroll
        for (int ks = 0; ks < 4; ++ks) {
            const int kk = khf * 4 + ks;
            short8 pa = *reinterpret_cast<const short8*>(
                Eb2 + ((kk * 64 + kg * 16) ^ swzr));
            short8 vb = ld8(vp + ks * 32 + kg * 8);
            acc = MFMA(pa, vb, acc);
        }
    };

    EWRITE(0, smem);
    __syncthreads();
    #pragma unroll
    for (int c = 0; c < 8; ++c) {
        char* curE = smem + ((c & 1) ? 8192 : 0);
        char* nxtE = smem + ((c & 1) ? 0 : 8192);
        if (c + 1 < 8) EWRITE(c + 1, nxtE);   // overlaps PV below
        PVSTEP(c, curE);
        __syncthreads();
    }

    // ---- CT exchange across k-halves (FINAL barrier), write ctx ----
    if (khf == 1) {
        #pragma unroll
        for (int i = 0; i < 4; ++i) CT[(kg * 4 + i) * 64 + c0 + r] = acc[i];
    }
    __syncthreads();
    if (khf == 0) {
        #pragma unroll
        for (int i = 0; i < 4; ++i) {
            const float val = acc[i] + CT[(kg * 4 + i) * 64 + c0 + r];
            ctxb[((size_t)bh * SEQ + q0 + kg * 4 + i) * HD + c0 + r] = f2bf(val);
        }
    }

    // ---- attn stream-out: AFTER the last barrier, fire-and-forget ----
    #pragma unroll
    for (int rr = 0; rr < 2; ++rr) {
        const int row = w + 8 * rr;
        const float iv = inv[rr];
        float* arow = attn + ((size_t)bh * SEQ + q0 + row) * SEQ + lane * 4;
        #pragma unroll
        for (int c = 0; c < 8; ++c) {
            f32x4 pv;
            pv[0] = __uint_as_float(u[rr][c * 4 + 0]) * iv;
            pv[1] = __uint_as_float(u[rr][c * 4 + 1]) * iv;
            pv[2] = __uint_as_float(u[rr][c * 4 + 2]) * iv;
            pv[3] = __uint_as_float(u[rr][c * 4 + 3]) * iv;
            __builtin_nontemporal_store(
                pv, reinterpret_cast<f32x4*>(arow + c * 256));
        }
    }
}

// ---------------- K4: out = ctx @ wo^T + bo (fp32 out) ---------------------
__global__ __launch_bounds__(256) void out_mfma(
    const short* __restrict__ ctxb, const short* __restrict__ wob,
    const float* __restrict__ bo, float* __restrict__ out)
{
    const int tid = threadIdx.x;
    const int w_  = tid >> 6, lane = tid & 63;
    const int r   = lane & 15, kg = lane >> 4;
    const int m_base = blockIdx.x * 128 + w_ * 32;
    const int n_base = blockIdx.y * 64;

    f32x4 acc[2][4] = {};

    for (int ks = 0; ks < 32; ++ks) {
        const int k0 = ks * 32 + kg * 8;
        const int h = k0 >> 6, hd = k0 & 63;
        short8 a[2];
        #pragma unroll
        for (int mf = 0; mf < 2; ++mf) {
            const int m = m_base + mf * 16 + r;
            const int b_ = m >> 11, s = m & 2047;
            a[mf] = ld8(ctxb + (((size_t)(b_ * NH + h)) * SEQ + s) * HD + hd);
        }
        #pragma unroll
        for (int nf = 0; nf < 4; ++nf) {
            short8 b = ld8(wob + (size_t)(n_base + nf * 16 + r) * DIMN + k0);
            acc[0][nf] = MFMA(a[0], b, acc[0][nf]);
            acc[1][nf] = MFMA(a[1], b, acc[1][nf]);
        }
    }

    #pragma unroll
    for (int mf = 0; mf < 2; ++mf)
        #pragma unroll
        for (int nf = 0; nf < 4; ++nf)
            #pragma unroll
            for (int i = 0; i < 4; ++i) {
                const int m  = m_base + mf * 16 + kg * 4 + i;
                const int nn = n_base + nf * 16 + r;
                out[(size_t)m * DIMN + nn] = acc[mf][nf][i] + bo[nn];
            }
}

extern "C" void kernel_launch(void* const* d_in, const int* in_sizes, int n_in,
                              void* d_out, int out_size, void* d_ws, size_t ws_size,
                              hipStream_t stream) {
    const float* x  = (const float*)d_in[0];
    const float* wq = (const float*)d_in[1];
    const float* bq = (const float*)d_in[2];
    const float* wk = (const float*)d_in[3];
    const float* bk = (const float*)d_in[4];
    const float* wv = (const float*)d_in[5];
    const float* bv = (const float*)d_in[6];
    const float* wo = (const float*)d_in[7];
    const float* bo = (const float*)d_in[8];

    float* out  = (float*)d_out;
    float* attn = out + (size_t)MROWS * DIMN;   // 512 MB region, written by fused_attn

    // --- scratch that dies before fused_attn runs: lives in the attn region ---
    short* xhi = (short*)attn;
    short* xlo = xhi + (size_t)MROWS * DIMN;
    short* wqh = xlo + (size_t)MROWS * DIMN;
    short* wql = wqh + (size_t)DIMN * DIMN;
    short* wkh = wql + (size_t)DIMN * DIMN;
    short* wkl = wkh + (size_t)DIMN * DIMN;
    short* wvb = wkl + (size_t)DIMN * DIMN;

    // --- scratch that must survive into/past fused_attn: lives in d_ws ---
    const size_t QKV = (size_t)BHN * SEQ * HD;  // 4,194,304
    short* qhi = (short*)d_ws;
    short* qlo = qhi + QKV;
    short* khi = qlo + QKV;
    short* klo = khi + QKV;
    short* vt  = klo + QKV;
    short* ctx = vt  + QKV;
    short* wob = ctx + QKV;

    conv_hilo<<<1024, 256, 0, stream>>>(x,  xhi, xlo, MROWS * DIMN);
    conv_hilo<<<512,  256, 0, stream>>>(wq, wqh, wql, DIMN * DIMN);
    conv_hilo<<<512,  256, 0, stream>>>(wk, wkh, wkl, DIMN * DIMN);
    conv_bf16<<<512,  256, 0, stream>>>(wv, wvb, DIMN * DIMN);
    conv_bf16<<<512,  256, 0, stream>>>(wo, wob, DIMN * DIMN);

    qk_mfma<<<dim3(MROWS / 128, DIMN / 64, 2), 256, 0, stream>>>(
        xhi, xlo, wqh, wql, bq, wkh, wkl, bk, qhi, qlo, khi, klo);
    v_mfma<<<dim3(MROWS / 128, DIMN / 64), 256, 0, stream>>>(
        xhi, xlo, wvb, bv, vt);

    fused_attn<<<dim3(SEQ / QROWS, BHN), 512, 0, stream>>>(
        qhi, qlo, khi, klo, vt, attn, ctx);

    out_mfma<<<dim3(MROWS / 128, DIMN / 64), 256, 0, stream>>>(ctx, wob, bo, out);
}

// Round 12
// 593.383 us; speedup vs baseline: 1.9824x; 1.3077x over previous
//
#include <hip/hip_runtime.h>
#include <hip/hip_bf16.h>

#define DIMN 1024
#define NH 16
#define HD 64
#define SEQ 2048
#define BATCH 2
#define BHN (BATCH*NH)        // 32
#define MROWS (BATCH*SEQ)     // 4096
#define KKEEP 409
#define SCALEF 0.125f
#define QROWS 16              // q-rows per block

typedef __attribute__((ext_vector_type(8))) short short8;
typedef __attribute__((ext_vector_type(4))) short short4v;
typedef __attribute__((ext_vector_type(4))) float f32x4;

#define MFMA(a,b,c) __builtin_amdgcn_mfma_f32_16x16x32_bf16(a,b,c,0,0,0)

// ---- Fragment-native tiled layouts (consumer wave-loads are contiguous 1KB):
// QT/KT (hi,lo): idx(bh,s,hd) = bh*131072 + (s>>4)*1024 + (hd>>5)*512
//                              + (((hd>>3)&3)*16 + (s&15))*8 + (hd&7)
// VT: idx(bh,s,hd) = bh*131072 + (hd>>4)*32768 + (s>>5)*512
//                   + (((s>>3)&3)*16 + (hd&15))*8 + (s&7)

static __device__ __forceinline__ short f2bf(float f) {
    __hip_bfloat16 h = __float2bfloat16(f);
    return *reinterpret_cast<short*>(&h);
}
static __device__ __forceinline__ float bf2f(short s) {
    __hip_bfloat16 h = *reinterpret_cast<__hip_bfloat16*>(&s);
    return __bfloat162float(h);
}
static __device__ __forceinline__ short8 ld8(const short* p) {
    return *reinterpret_cast<const short8*>(p);
}
// inverse of the monotone float->uint key map
static __device__ __forceinline__ float keyf(unsigned u) {
    unsigned fu = (u & 0x80000000u) ? (u ^ 0x80000000u) : ~u;
    return __uint_as_float(fu);
}

// ---------------- K0a: fp32 -> (hi, lo) bf16 pair --------------------------
__global__ void conv_hilo(const float* __restrict__ in,
                          short* __restrict__ hi, short* __restrict__ lo, int n) {
    const int n4 = n >> 2;
    for (int i = blockIdx.x * blockDim.x + threadIdx.x; i < n4;
         i += gridDim.x * blockDim.x) {
        float4 v = reinterpret_cast<const float4*>(in)[i];
        short4v h, l;
        #pragma unroll
        for (int j = 0; j < 4; ++j) {
            float f = (&v.x)[j];
            short hb = f2bf(f);
            h[j] = hb;
            l[j] = f2bf(f - bf2f(hb));
        }
        reinterpret_cast<short4v*>(hi)[i] = h;
        reinterpret_cast<short4v*>(lo)[i] = l;
    }
}

// ---------------- K0b: fp32 -> bf16 ----------------------------------------
__global__ void conv_bf16(const float* __restrict__ in, short* __restrict__ out, int n) {
    const int n4 = n >> 2;
    for (int i = blockIdx.x * blockDim.x + threadIdx.x; i < n4;
         i += gridDim.x * blockDim.x) {
        float4 v = reinterpret_cast<const float4*>(in)[i];
        short4v o;
        o[0] = f2bf(v.x); o[1] = f2bf(v.y); o[2] = f2bf(v.z); o[3] = f2bf(v.w);
        reinterpret_cast<short4v*>(out)[i] = o;
    }
}

// ---------------- K1: Q/K projection, hi/lo precision, TILED output --------
__global__ __launch_bounds__(256) void qk_mfma(
    const short* __restrict__ xh, const short* __restrict__ xl,
    const short* __restrict__ wqh, const short* __restrict__ wql, const float* __restrict__ bq,
    const short* __restrict__ wkh, const short* __restrict__ wkl, const float* __restrict__ bk,
    short* __restrict__ qhi, short* __restrict__ qlo,
    short* __restrict__ khi, short* __restrict__ klo)
{
    const int z = blockIdx.z;
    const short* wh = z ? wkh : wqh;
    const short* wl = z ? wkl : wql;
    const float* bias = z ? bk : bq;
    short* dhi = z ? khi : qhi;
    short* dlo = z ? klo : qlo;

    const int tid  = threadIdx.x;
    const int wv_  = tid >> 6, lane = tid & 63;
    const int r    = lane & 15, kg = lane >> 4;
    const int m_base = blockIdx.x * 128 + wv_ * 32;
    const int n_base = blockIdx.y * 64;

    f32x4 acc[2][4] = {};

    for (int ks = 0; ks < 32; ++ks) {
        const int k0 = ks * 32 + kg * 8;
        short8 ah0 = ld8(xh + (size_t)(m_base + r) * DIMN + k0);
        short8 al0 = ld8(xl + (size_t)(m_base + r) * DIMN + k0);
        short8 ah1 = ld8(xh + (size_t)(m_base + 16 + r) * DIMN + k0);
        short8 al1 = ld8(xl + (size_t)(m_base + 16 + r) * DIMN + k0);
        #pragma unroll
        for (int nf = 0; nf < 4; ++nf) {
            short8 bh = ld8(wh + (size_t)(n_base + nf * 16 + r) * DIMN + k0);
            short8 bl = ld8(wl + (size_t)(n_base + nf * 16 + r) * DIMN + k0);
            acc[0][nf] = MFMA(ah0, bh, acc[0][nf]);
            acc[0][nf] = MFMA(ah0, bl, acc[0][nf]);
            acc[0][nf] = MFMA(al0, bh, acc[0][nf]);
            acc[1][nf] = MFMA(ah1, bh, acc[1][nf]);
            acc[1][nf] = MFMA(ah1, bl, acc[1][nf]);
            acc[1][nf] = MFMA(al1, bh, acc[1][nf]);
        }
    }

    const int h = blockIdx.y;
    #pragma unroll
    for (int mf = 0; mf < 2; ++mf)
        #pragma unroll
        for (int nf = 0; nf < 4; ++nf)
            #pragma unroll
            for (int i = 0; i < 4; ++i) {
                const int m  = m_base + mf * 16 + kg * 4 + i;
                const int nn = n_base + nf * 16 + r;
                const float val = acc[mf][nf][i] + bias[nn];
                const int b_ = m >> 11, s = m & 2047;
                const int hd = nf * 16 + r;
                const size_t idx = (size_t)(b_ * NH + h) * 131072
                    + (size_t)(s >> 4) * 1024 + (hd >> 5) * 512
                    + ((((hd >> 3) & 3) * 16 + (s & 15)) * 8) + (hd & 7);
                const short hb = f2bf(val);
                dhi[idx] = hb;
                dlo[idx] = f2bf(val - bf2f(hb));
            }
}

// ---------------- K2: V projection (2-MFMA), TILED V^T output --------------
__global__ __launch_bounds__(256) void v_mfma(
    const short* __restrict__ xh, const short* __restrict__ xl,
    const short* __restrict__ wvb, const float* __restrict__ bv,
    short* __restrict__ vt)
{
    const int tid  = threadIdx.x;
    const int wv_  = tid >> 6, lane = tid & 63;
    const int r    = lane & 15, kg = lane >> 4;
    const int m_base = blockIdx.x * 128 + wv_ * 32;
    const int n_base = blockIdx.y * 64;

    f32x4 acc[2][4] = {};

    for (int ks = 0; ks < 32; ++ks) {
        const int k0 = ks * 32 + kg * 8;
        short8 ah0 = ld8(xh + (size_t)(m_base + r) * DIMN + k0);
        short8 al0 = ld8(xl + (size_t)(m_base + r) * DIMN + k0);
        short8 ah1 = ld8(xh + (size_t)(m_base + 16 + r) * DIMN + k0);
        short8 al1 = ld8(xl + (size_t)(m_base + 16 + r) * DIMN + k0);
        #pragma unroll
        for (int nf = 0; nf < 4; ++nf) {
            short8 b = ld8(wvb + (size_t)(n_base + nf * 16 + r) * DIMN + k0);
            acc[0][nf] = MFMA(ah0, b, acc[0][nf]);
            acc[0][nf] = MFMA(al0, b, acc[0][nf]);
            acc[1][nf] = MFMA(ah1, b, acc[1][nf]);
            acc[1][nf] = MFMA(al1, b, acc[1][nf]);
        }
    }

    const int h = blockIdx.y;
    #pragma unroll
    for (int mf = 0; mf < 2; ++mf)
        #pragma unroll
        for (int nf = 0; nf < 4; ++nf)
            #pragma unroll
            for (int i = 0; i < 4; ++i) {
                const int m  = m_base + mf * 16 + kg * 4 + i;
                const int nn = n_base + nf * 16 + r;
                const float val = acc[mf][nf][i] + bv[nn];
                const int b_ = m >> 11, s = m & 2047;
                const int hd = nf * 16 + r;
                const size_t idx = (size_t)(b_ * NH + h) * 131072
                    + (size_t)(hd >> 4) * 32768 + (size_t)(s >> 5) * 512
                    + ((((s >> 3) & 3) * 16 + (hd & 15)) * 8) + (s & 7);
                vt[idx] = f2bf(val);
            }
}

// ---------------- K3: fused scores + exact top-k + softmax + PV ------------
// 512 threads = 8 waves; 16 q-rows; LDS 32 KB; 2 blocks/CU. All Q/K/V
// fragment loads are now contiguous 1KB wave-loads from the tiled layouts
// (previously 16-segment gathers -> L2 transaction-latency bound).
__global__ __launch_bounds__(512, 4) void fused_attn(
    const short* __restrict__ qh, const short* __restrict__ ql,
    const short* __restrict__ kh, const short* __restrict__ kl,
    const short* __restrict__ vtb, float* __restrict__ attn,
    short* __restrict__ ctxb)
{
    __shared__ __align__(16) char smem[32768];
    // Phase A: CB0 fp32[16][256] @0, CB1 @16384
    // Phase C: E0 bf16[16][256] @0 (8KB), E1 @8192, CT fp32[16][64] @16384
    float* CT = (float*)(smem + 16384);

    const int tid = threadIdx.x;
    const int w   = tid >> 6, lane = tid & 63;
    const int r   = lane & 15, kg = lane >> 4;
    const int bh  = blockIdx.y;
    const int q0  = blockIdx.x * QROWS;

    // ---- Phase A: S = SCALE*Q K^T, 8 chunks of 256 cols, pipelined ----
    const size_t qtbase = (size_t)bh * 131072 + (size_t)blockIdx.x * 1024 + lane * 8;
    short8 a0h = ld8(qh + qtbase),       a0l = ld8(ql + qtbase);
    short8 a1h = ld8(qh + qtbase + 512), a1l = ld8(ql + qtbase + 512);

    unsigned u[2][32];

    auto STAGE = [&](int c, float* buf) {
        #pragma unroll
        for (int tt = 0; tt < 2; ++tt) {
            const int stile = c * 16 + w + 8 * tt;
            const size_t tb = (size_t)bh * 131072 + (size_t)stile * 1024 + lane * 8;
            short8 b0h = ld8(kh + tb);
            short8 b0l = ld8(kl + tb);
            short8 b1h = ld8(kh + tb + 512);
            short8 b1l = ld8(kl + tb + 512);
            f32x4 accA = {0.f, 0.f, 0.f, 0.f};
            f32x4 accB = {0.f, 0.f, 0.f, 0.f};
            accA = MFMA(a0h, b0h, accA);
            accB = MFMA(a1h, b1h, accB);
            accA = MFMA(a0h, b0l, accA);
            accB = MFMA(a1h, b1l, accB);
            accA = MFMA(a0l, b0h, accA);
            accB = MFMA(a1l, b1h, accB);
            const int j0c = (w + 8 * tt) * 16;
            #pragma unroll
            for (int i = 0; i < 4; ++i)
                buf[(kg * 4 + i) * 256 + j0c + r] = (accA[i] + accB[i]) * SCALEF;
        }
    };

    STAGE(0, (float*)smem);
    __syncthreads();
    #pragma unroll
    for (int c = 0; c < 8; ++c) {
        float* cur = (float*)(smem + ((c & 1) ? 16384 : 0));
        float* nxt = (float*)(smem + ((c & 1) ? 0 : 16384));
        if (c + 1 < 8) STAGE(c + 1, nxt);     // overlaps PULL below
        #pragma unroll
        for (int rr = 0; rr < 2; ++rr) {
            const float* src = cur + (w + 8 * rr) * 256;
            f32x4 v4 = *reinterpret_cast<const f32x4*>(src + lane * 4);
            #pragma unroll
            for (int q_ = 0; q_ < 4; ++q_) {
                unsigned fu = __float_as_uint(v4[q_]);
                u[rr][c * 4 + q_] = (fu & 0x80000000u) ? ~fu : (fu | 0x80000000u);
            }
        }
        __syncthreads();
    }

    // ---- Phase B-1: early-exit exact radix top-k + softmax (regs only) ----
    float inv[2];
    #pragma unroll
    for (int rr = 0; rr < 2; ++rr) {
        unsigned cur = 0;
        for (int bit = 31; bit >= 0; --bit) {
            const unsigned cand = cur | (1u << bit);
            int cnt = 0;
            #pragma unroll
            for (int jj = 0; jj < 32; ++jj)
                cnt += __popcll(__ballot(u[rr][jj] >= cand));
            if (cnt >= KKEEP) {
                cur = cand;
                if (cnt == KKEEP) break;   // kept set finalized: bit-exact
            }
        }
        unsigned mu = 0;
        #pragma unroll
        for (int jj = 0; jj < 32; ++jj) mu = (u[rr][jj] > mu) ? u[rr][jj] : mu;
        #pragma unroll
        for (int off = 32; off; off >>= 1) {
            unsigned o = (unsigned)__shfl_xor((int)mu, off);
            mu = (o > mu) ? o : mu;
        }
        const float m = keyf(mu);
        float denom = 0.f;
        #pragma unroll
        for (int jj = 0; jj < 32; ++jj) {
            const unsigned ue = u[rr][jj];
            const float e = (ue >= cur) ? __expf(keyf(ue) - m) : 0.f;
            u[rr][jj] = __float_as_uint(e);   // key -> unnormalized exp
            denom += e;
        }
        #pragma unroll
        for (int off = 32; off; off >>= 1) denom += __shfl_xor(denom, off);
        inv[rr] = 1.0f / denom;
    }

    // ---- Phase C: 8x 256-col chunks; E double-buffered; LDS writes only ----
    const int khf = w >> 2;            // k-half within chunk (128 cols)
    const int swzw = (w & 7) << 4;     // write swizzle
    const int swzr = (r & 7) << 4;     // read swizzle
    f32x4 acc = {0.f, 0.f, 0.f, 0.f};

    auto EWRITE = [&](int c, char* Ebase) {
        #pragma unroll
        for (int rr = 0; rr < 2; ++rr) {
            const int row = w + 8 * rr;
            const float iv = inv[rr];
            short4v pb;
            pb[0] = f2bf(__uint_as_float(u[rr][c * 4 + 0]) * iv);
            pb[1] = f2bf(__uint_as_float(u[rr][c * 4 + 1]) * iv);
            pb[2] = f2bf(__uint_as_float(u[rr][c * 4 + 2]) * iv);
            pb[3] = f2bf(__uint_as_float(u[rr][c * 4 + 3]) * iv);
            *reinterpret_cast<short4v*>(
                Ebase + row * 512 + ((lane * 8) ^ swzw)) = pb;
        }
    };
    auto PVSTEP = [&](int c, const char* Ebase) {
        const size_t vbase = (size_t)bh * 131072 + (size_t)(w & 3) * 32768
                           + (size_t)(c * 8 + khf * 4) * 512 + lane * 8;
        const char* Eb2 = Ebase + r * 512;
        #pragma unroll
        for (int ks = 0; ks < 4; ++ks) {
            const int kk = khf * 4 + ks;
            short8 pa = *reinterpret_cast<const short8*>(
                Eb2 + ((kk * 64 + kg * 16) ^ swzr));
            short8 vb = ld8(vtb + vbase + ks * 512);
            acc = MFMA(pa, vb, acc);
        }
    };

    EWRITE(0, smem);
    __syncthreads();
    #pragma unroll
    for (int c = 0; c < 8; ++c) {
        char* curE = smem + ((c & 1) ? 8192 : 0);
        char* nxtE = smem + ((c & 1) ? 0 : 8192);
        if (c + 1 < 8) EWRITE(c + 1, nxtE);   // overlaps PV below
        PVSTEP(c, curE);
        __syncthreads();
    }

    // ---- CT exchange across k-halves (FINAL barrier), write ctx ----
    const int c0 = (w & 3) * 16;
    if (khf == 1) {
        #pragma unroll
        for (int i = 0; i < 4; ++i) CT[(kg * 4 + i) * 64 + c0 + r] = acc[i];
    }
    __syncthreads();
    if (khf == 0) {
        #pragma unroll
        for (int i = 0; i < 4; ++i) {
            const float val = acc[i] + CT[(kg * 4 + i) * 64 + c0 + r];
            ctxb[((size_t)bh * SEQ + q0 + kg * 4 + i) * HD + c0 + r] = f2bf(val);
        }
    }

    // ---- attn stream-out: AFTER the last barrier, fire-and-forget ----
    #pragma unroll
    for (int rr = 0; rr < 2; ++rr) {
        const int row = w + 8 * rr;
        const float iv = inv[rr];
        float* arow = attn + ((size_t)bh * SEQ + q0 + row) * SEQ + lane * 4;
        #pragma unroll
        for (int c = 0; c < 8; ++c) {
            f32x4 pv;
            pv[0] = __uint_as_float(u[rr][c * 4 + 0]) * iv;
            pv[1] = __uint_as_float(u[rr][c * 4 + 1]) * iv;
            pv[2] = __uint_as_float(u[rr][c * 4 + 2]) * iv;
            pv[3] = __uint_as_float(u[rr][c * 4 + 3]) * iv;
            __builtin_nontemporal_store(
                pv, reinterpret_cast<f32x4*>(arow + c * 256));
        }
    }
}

// ---------------- K4: out = ctx @ wo^T + bo (fp32 out) ---------------------
__global__ __launch_bounds__(256) void out_mfma(
    const short* __restrict__ ctxb, const short* __restrict__ wob,
    const float* __restrict__ bo, float* __restrict__ out)
{
    const int tid = threadIdx.x;
    const int w_  = tid >> 6, lane = tid & 63;
    const int r   = lane & 15, kg = lane >> 4;
    const int m_base = blockIdx.x * 128 + w_ * 32;
    const int n_base = blockIdx.y * 64;

    f32x4 acc[2][4] = {};

    for (int ks = 0; ks < 32; ++ks) {
        const int k0 = ks * 32 + kg * 8;
        const int h = k0 >> 6, hd = k0 & 63;
        short8 a[2];
        #pragma unroll
        for (int mf = 0; mf < 2; ++mf) {
            const int m = m_base + mf * 16 + r;
            const int b_ = m >> 11, s = m & 2047;
            a[mf] = ld8(ctxb + (((size_t)(b_ * NH + h)) * SEQ + s) * HD + hd);
        }
        #pragma unroll
        for (int nf = 0; nf < 4; ++nf) {
            short8 b = ld8(wob + (size_t)(n_base + nf * 16 + r) * DIMN + k0);
            acc[0][nf] = MFMA(a[0], b, acc[0][nf]);
            acc[1][nf] = MFMA(a[1], b, acc[1][nf]);
        }
    }

    #pragma unroll
    for (int mf = 0; mf < 2; ++mf)
        #pragma unroll
        for (int nf = 0; nf < 4; ++nf)
            #pragma unroll
            for (int i = 0; i < 4; ++i) {
                const int m  = m_base + mf * 16 + kg * 4 + i;
                const int nn = n_base + nf * 16 + r;
                out[(size_t)m * DIMN + nn] = acc[mf][nf][i] + bo[nn];
            }
}

extern "C" void kernel_launch(void* const* d_in, const int* in_sizes, int n_in,
                              void* d_out, int out_size, void* d_ws, size_t ws_size,
                              hipStream_t stream) {
    const float* x  = (const float*)d_in[0];
    const float* wq = (const float*)d_in[1];
    const float* bq = (const float*)d_in[2];
    const float* wk = (const float*)d_in[3];
    const float* bk = (const float*)d_in[4];
    const float* wv = (const float*)d_in[5];
    const float* bv = (const float*)d_in[6];
    const float* wo = (const float*)d_in[7];
    const float* bo = (const float*)d_in[8];

    float* out  = (float*)d_out;
    float* attn = out + (size_t)MROWS * DIMN;   // 512 MB region, written by fused_attn

    // --- scratch that dies before fused_attn runs: lives in the attn region ---
    short* xhi = (short*)attn;
    short* xlo = xhi + (size_t)MROWS * DIMN;
    short* wqh = xlo + (size_t)MROWS * DIMN;
    short* wql = wqh + (size_t)DIMN * DIMN;
    short* wkh = wql + (size_t)DIMN * DIMN;
    short* wkl = wkh + (size_t)DIMN * DIMN;
    short* wvb = wkl + (size_t)DIMN * DIMN;

    // --- scratch that must survive into/past fused_attn: lives in d_ws ---
    const size_t QKV = (size_t)BHN * SEQ * HD;  // 4,194,304
    short* qhi = (short*)d_ws;
    short* qlo = qhi + QKV;
    short* khi = qlo + QKV;
    short* klo = khi + QKV;
    short* vt  = klo + QKV;
    short* ctx = vt  + QKV;
    short* wob = ctx + QKV;

    conv_hilo<<<1024, 256, 0, stream>>>(x,  xhi, xlo, MROWS * DIMN);
    conv_hilo<<<512,  256, 0, stream>>>(wq, wqh, wql, DIMN * DIMN);
    conv_hilo<<<512,  256, 0, stream>>>(wk, wkh, wkl, DIMN * DIMN);
    conv_bf16<<<512,  256, 0, stream>>>(wv, wvb, DIMN * DIMN);
    conv_bf16<<<512,  256, 0, stream>>>(wo, wob, DIMN * DIMN);

    qk_mfma<<<dim3(MROWS / 128, DIMN / 64, 2), 256, 0, stream>>>(
        xhi, xlo, wqh, wql, bq, wkh, wkl, bk, qhi, qlo, khi, klo);
    v_mfma<<<dim3(MROWS / 128, DIMN / 64), 256, 0, stream>>>(
        xhi, xlo, wvb, bv, vt);

    fused_attn<<<dim3(SEQ / QROWS, BHN), 512, 0, stream>>>(
        qhi, qlo, khi, klo, vt, attn, ctx);

    out_mfma<<<dim3(MROWS / 128, DIMN / 64), 256, 0, stream>>>(ctx, wob, bo, out);
}

// Round 13
// 437.949 us; speedup vs baseline: 2.6860x; 1.3549x over previous
//
#include <hip/hip_runtime.h>
#include <hip/hip_bf16.h>

#define DIMN 1024
#define NH 16
#define HD 64
#define SEQ 2048
#define BATCH 2
#define BHN (BATCH*NH)        // 32
#define MROWS (BATCH*SEQ)     // 4096
#define KKEEP 409
#define SCALEF 0.125f
#define QROWS 16              // q-rows per block

typedef __attribute__((ext_vector_type(8))) short short8;
typedef __attribute__((ext_vector_type(4))) short short4v;
typedef __attribute__((ext_vector_type(4))) float f32x4;

#define MFMA(a,b,c) __builtin_amdgcn_mfma_f32_16x16x32_bf16(a,b,c,0,0,0)

// ---- Universal MFMA-fragment tile layout for [rows][1024] operands:
// T(m,k) = (m>>4)*16384 + (k>>5)*512 + (((k>>3)&3)*16 + (m&15))*8 + (k&7)
// A wave's fragment load (16 rows x 8 k-elems) is one contiguous 1KB block.
// QT/KT (per bh): bh*131072 + (s>>4)*1024 + (hd>>5)*512 + (((hd>>3)&3)*16+(s&15))*8 + (hd&7)
// VT  (per bh): bh*131072 + (hd>>4)*32768 + (s>>5)*512 + (((s>>3)&3)*16+(hd&15))*8 + (s&7)

static __device__ __forceinline__ short f2bf(float f) {
    __hip_bfloat16 h = __float2bfloat16(f);
    return *reinterpret_cast<short*>(&h);
}
static __device__ __forceinline__ float bf2f(short s) {
    __hip_bfloat16 h = *reinterpret_cast<__hip_bfloat16*>(&s);
    return __bfloat162float(h);
}
static __device__ __forceinline__ short8 ld8(const short* p) {
    return *reinterpret_cast<const short8*>(p);
}
static __device__ __forceinline__ float keyf(unsigned u) {
    unsigned fu = (u & 0x80000000u) ? (u ^ 0x80000000u) : ~u;
    return __uint_as_float(fu);
}
static __device__ __forceinline__ size_t tidx(int row, int k) {
    return (size_t)(row >> 4) * 16384 + (size_t)(k >> 5) * 512
         + ((((k >> 3) & 3) * 16 + (row & 15)) * 8) + (k & 7);
}

// ---------------- K0a: fp32 -> (hi, lo) bf16 pair, TILED output ------------
__global__ void conv_hilo_t(const float* __restrict__ in,
                            short* __restrict__ hi, short* __restrict__ lo, int rows) {
    const int total = rows * 256;     // 4 elems per thread
    for (int idx = blockIdx.x * blockDim.x + threadIdx.x; idx < total;
         idx += gridDim.x * blockDim.x) {
        const int row = idx >> 8;
        const int k = (idx & 255) * 4;
        float4 v = *reinterpret_cast<const float4*>(in + (size_t)row * DIMN + k);
        short4v h, l;
        #pragma unroll
        for (int j = 0; j < 4; ++j) {
            float f = (&v.x)[j];
            short hb = f2bf(f);
            h[j] = hb;
            l[j] = f2bf(f - bf2f(hb));
        }
        const size_t o = tidx(row, k);
        *reinterpret_cast<short4v*>(hi + o) = h;
        *reinterpret_cast<short4v*>(lo + o) = l;
    }
}

// ---------------- K0b: fp32 -> bf16, TILED output ---------------------------
__global__ void conv_bf16_t(const float* __restrict__ in,
                            short* __restrict__ out, int rows) {
    const int total = rows * 256;
    for (int idx = blockIdx.x * blockDim.x + threadIdx.x; idx < total;
         idx += gridDim.x * blockDim.x) {
        const int row = idx >> 8;
        const int k = (idx & 255) * 4;
        float4 v = *reinterpret_cast<const float4*>(in + (size_t)row * DIMN + k);
        short4v o;
        o[0] = f2bf(v.x); o[1] = f2bf(v.y); o[2] = f2bf(v.z); o[3] = f2bf(v.w);
        *reinterpret_cast<short4v*>(out + tidx(row, k)) = o;
    }
}

// ---------------- K1: Q/K projection, hi/lo precision, tiled in+out --------
__global__ __launch_bounds__(256) void qk_mfma(
    const short* __restrict__ xh, const short* __restrict__ xl,
    const short* __restrict__ wqh, const short* __restrict__ wql, const float* __restrict__ bq,
    const short* __restrict__ wkh, const short* __restrict__ wkl, const float* __restrict__ bk,
    short* __restrict__ qhi, short* __restrict__ qlo,
    short* __restrict__ khi, short* __restrict__ klo)
{
    const int z = blockIdx.z;
    const short* wh = z ? wkh : wqh;
    const short* wl = z ? wkl : wql;
    const float* bias = z ? bk : bq;
    short* dhi = z ? khi : qhi;
    short* dlo = z ? klo : qlo;

    const int tid  = threadIdx.x;
    const int wv_  = tid >> 6, lane = tid & 63;
    const int r    = lane & 15, kg = lane >> 4;
    const int m_base = blockIdx.x * 128 + wv_ * 32;
    const int n_base = blockIdx.y * 64;
    const int mtile0 = blockIdx.x * 8 + wv_ * 2;
    const int ntile0 = blockIdx.y * 4;

    f32x4 acc[2][4] = {};

    for (int ks = 0; ks < 32; ++ks) {
        short8 ah0 = ld8(xh + (size_t)mtile0 * 16384 + ks * 512 + lane * 8);
        short8 al0 = ld8(xl + (size_t)mtile0 * 16384 + ks * 512 + lane * 8);
        short8 ah1 = ld8(xh + (size_t)(mtile0 + 1) * 16384 + ks * 512 + lane * 8);
        short8 al1 = ld8(xl + (size_t)(mtile0 + 1) * 16384 + ks * 512 + lane * 8);
        #pragma unroll
        for (int nf = 0; nf < 4; ++nf) {
            short8 bh = ld8(wh + (size_t)(ntile0 + nf) * 16384 + ks * 512 + lane * 8);
            short8 bl = ld8(wl + (size_t)(ntile0 + nf) * 16384 + ks * 512 + lane * 8);
            acc[0][nf] = MFMA(ah0, bh, acc[0][nf]);
            acc[0][nf] = MFMA(ah0, bl, acc[0][nf]);
            acc[0][nf] = MFMA(al0, bh, acc[0][nf]);
            acc[1][nf] = MFMA(ah1, bh, acc[1][nf]);
            acc[1][nf] = MFMA(ah1, bl, acc[1][nf]);
            acc[1][nf] = MFMA(al1, bh, acc[1][nf]);
        }
    }

    const int h = blockIdx.y;
    #pragma unroll
    for (int mf = 0; mf < 2; ++mf)
        #pragma unroll
        for (int nf = 0; nf < 4; ++nf)
            #pragma unroll
            for (int i = 0; i < 4; ++i) {
                const int m  = m_base + mf * 16 + kg * 4 + i;
                const int nn = n_base + nf * 16 + r;
                const float val = acc[mf][nf][i] + bias[nn];
                const int b_ = m >> 11, s = m & 2047;
                const int hd = nf * 16 + r;
                const size_t idx = (size_t)(b_ * NH + h) * 131072
                    + (size_t)(s >> 4) * 1024 + (hd >> 5) * 512
                    + ((((hd >> 3) & 3) * 16 + (s & 15)) * 8) + (hd & 7);
                const short hb = f2bf(val);
                dhi[idx] = hb;
                dlo[idx] = f2bf(val - bf2f(hb));
            }
}

// ---------------- K2: V projection (2-MFMA), tiled in, tiled V^T out -------
__global__ __launch_bounds__(256) void v_mfma(
    const short* __restrict__ xh, const short* __restrict__ xl,
    const short* __restrict__ wvb, const float* __restrict__ bv,
    short* __restrict__ vt)
{
    const int tid  = threadIdx.x;
    const int wv_  = tid >> 6, lane = tid & 63;
    const int r    = lane & 15, kg = lane >> 4;
    const int m_base = blockIdx.x * 128 + wv_ * 32;
    const int n_base = blockIdx.y * 64;
    const int mtile0 = blockIdx.x * 8 + wv_ * 2;
    const int ntile0 = blockIdx.y * 4;

    f32x4 acc[2][4] = {};

    for (int ks = 0; ks < 32; ++ks) {
        short8 ah0 = ld8(xh + (size_t)mtile0 * 16384 + ks * 512 + lane * 8);
        short8 al0 = ld8(xl + (size_t)mtile0 * 16384 + ks * 512 + lane * 8);
        short8 ah1 = ld8(xh + (size_t)(mtile0 + 1) * 16384 + ks * 512 + lane * 8);
        short8 al1 = ld8(xl + (size_t)(mtile0 + 1) * 16384 + ks * 512 + lane * 8);
        #pragma unroll
        for (int nf = 0; nf < 4; ++nf) {
            short8 b = ld8(wvb + (size_t)(ntile0 + nf) * 16384 + ks * 512 + lane * 8);
            acc[0][nf] = MFMA(ah0, b, acc[0][nf]);
            acc[0][nf] = MFMA(al0, b, acc[0][nf]);
            acc[1][nf] = MFMA(ah1, b, acc[1][nf]);
            acc[1][nf] = MFMA(al1, b, acc[1][nf]);
        }
    }

    const int h = blockIdx.y;
    #pragma unroll
    for (int mf = 0; mf < 2; ++mf)
        #pragma unroll
        for (int nf = 0; nf < 4; ++nf)
            #pragma unroll
            for (int i = 0; i < 4; ++i) {
                const int m  = m_base + mf * 16 + kg * 4 + i;
                const int nn = n_base + nf * 16 + r;
                const float val = acc[mf][nf][i] + bv[nn];
                const int b_ = m >> 11, s = m & 2047;
                const int hd = nf * 16 + r;
                const size_t idx = (size_t)(b_ * NH + h) * 131072
                    + (size_t)(hd >> 4) * 32768 + (size_t)(s >> 5) * 512
                    + ((((s >> 3) & 3) * 16 + (hd & 15)) * 8) + (s & 7);
                vt[idx] = f2bf(val);
            }
}

// ---------------- K3: fused scores + exact top-k + softmax + PV ------------
// Unchanged from R12 except ctx is written in the universal tile layout.
__global__ __launch_bounds__(512, 4) void fused_attn(
    const short* __restrict__ qh, const short* __restrict__ ql,
    const short* __restrict__ kh, const short* __restrict__ kl,
    const short* __restrict__ vtb, float* __restrict__ attn,
    short* __restrict__ ctxt)
{
    __shared__ __align__(16) char smem[32768];
    float* CT = (float*)(smem + 16384);

    const int tid = threadIdx.x;
    const int w   = tid >> 6, lane = tid & 63;
    const int r   = lane & 15, kg = lane >> 4;
    const int bh  = blockIdx.y;
    const int q0  = blockIdx.x * QROWS;

    // ---- Phase A ----
    const size_t qtbase = (size_t)bh * 131072 + (size_t)blockIdx.x * 1024 + lane * 8;
    short8 a0h = ld8(qh + qtbase),       a0l = ld8(ql + qtbase);
    short8 a1h = ld8(qh + qtbase + 512), a1l = ld8(ql + qtbase + 512);

    unsigned u[2][32];

    auto STAGE = [&](int c, float* buf) {
        #pragma unroll
        for (int tt = 0; tt < 2; ++tt) {
            const int stile = c * 16 + w + 8 * tt;
            const size_t tb = (size_t)bh * 131072 + (size_t)stile * 1024 + lane * 8;
            short8 b0h = ld8(kh + tb);
            short8 b0l = ld8(kl + tb);
            short8 b1h = ld8(kh + tb + 512);
            short8 b1l = ld8(kl + tb + 512);
            f32x4 accA = {0.f, 0.f, 0.f, 0.f};
            f32x4 accB = {0.f, 0.f, 0.f, 0.f};
            accA = MFMA(a0h, b0h, accA);
            accB = MFMA(a1h, b1h, accB);
            accA = MFMA(a0h, b0l, accA);
            accB = MFMA(a1h, b1l, accB);
            accA = MFMA(a0l, b0h, accA);
            accB = MFMA(a1l, b1h, accB);
            const int j0c = (w + 8 * tt) * 16;
            #pragma unroll
            for (int i = 0; i < 4; ++i)
                buf[(kg * 4 + i) * 256 + j0c + r] = (accA[i] + accB[i]) * SCALEF;
        }
    };

    STAGE(0, (float*)smem);
    __syncthreads();
    #pragma unroll
    for (int c = 0; c < 8; ++c) {
        float* cur = (float*)(smem + ((c & 1) ? 16384 : 0));
        float* nxt = (float*)(smem + ((c & 1) ? 0 : 16384));
        if (c + 1 < 8) STAGE(c + 1, nxt);
        #pragma unroll
        for (int rr = 0; rr < 2; ++rr) {
            const float* src = cur + (w + 8 * rr) * 256;
            f32x4 v4 = *reinterpret_cast<const f32x4*>(src + lane * 4);
            #pragma unroll
            for (int q_ = 0; q_ < 4; ++q_) {
                unsigned fu = __float_as_uint(v4[q_]);
                u[rr][c * 4 + q_] = (fu & 0x80000000u) ? ~fu : (fu | 0x80000000u);
            }
        }
        __syncthreads();
    }

    // ---- Phase B-1: early-exit exact radix top-k + softmax ----
    float inv[2];
    #pragma unroll
    for (int rr = 0; rr < 2; ++rr) {
        unsigned cur = 0;
        for (int bit = 31; bit >= 0; --bit) {
            const unsigned cand = cur | (1u << bit);
            int cnt = 0;
            #pragma unroll
            for (int jj = 0; jj < 32; ++jj)
                cnt += __popcll(__ballot(u[rr][jj] >= cand));
            if (cnt >= KKEEP) {
                cur = cand;
                if (cnt == KKEEP) break;
            }
        }
        unsigned mu = 0;
        #pragma unroll
        for (int jj = 0; jj < 32; ++jj) mu = (u[rr][jj] > mu) ? u[rr][jj] : mu;
        #pragma unroll
        for (int off = 32; off; off >>= 1) {
            unsigned o = (unsigned)__shfl_xor((int)mu, off);
            mu = (o > mu) ? o : mu;
        }
        const float m = keyf(mu);
        float denom = 0.f;
        #pragma unroll
        for (int jj = 0; jj < 32; ++jj) {
            const unsigned ue = u[rr][jj];
            const float e = (ue >= cur) ? __expf(keyf(ue) - m) : 0.f;
            u[rr][jj] = __float_as_uint(e);
            denom += e;
        }
        #pragma unroll
        for (int off = 32; off; off >>= 1) denom += __shfl_xor(denom, off);
        inv[rr] = 1.0f / denom;
    }

    // ---- Phase C ----
    const int khf = w >> 2;
    const int swzw = (w & 7) << 4;
    const int swzr = (r & 7) << 4;
    f32x4 acc = {0.f, 0.f, 0.f, 0.f};

    auto EWRITE = [&](int c, char* Ebase) {
        #pragma unroll
        for (int rr = 0; rr < 2; ++rr) {
            const int row = w + 8 * rr;
            const float iv = inv[rr];
            short4v pb;
            pb[0] = f2bf(__uint_as_float(u[rr][c * 4 + 0]) * iv);
            pb[1] = f2bf(__uint_as_float(u[rr][c * 4 + 1]) * iv);
            pb[2] = f2bf(__uint_as_float(u[rr][c * 4 + 2]) * iv);
            pb[3] = f2bf(__uint_as_float(u[rr][c * 4 + 3]) * iv);
            *reinterpret_cast<short4v*>(
                Ebase + row * 512 + ((lane * 8) ^ swzw)) = pb;
        }
    };
    auto PVSTEP = [&](int c, const char* Ebase) {
        const size_t vbase = (size_t)bh * 131072 + (size_t)(w & 3) * 32768
                           + (size_t)(c * 8 + khf * 4) * 512 + lane * 8;
        const char* Eb2 = Ebase + r * 512;
        #pragma unroll
        for (int ks = 0; ks < 4; ++ks) {
            const int kk = khf * 4 + ks;
            short8 pa = *reinterpret_cast<const short8*>(
                Eb2 + ((kk * 64 + kg * 16) ^ swzr));
            short8 vb = ld8(vtb + vbase + ks * 512);
            acc = MFMA(pa, vb, acc);
        }
    };

    EWRITE(0, smem);
    __syncthreads();
    #pragma unroll
    for (int c = 0; c < 8; ++c) {
        char* curE = smem + ((c & 1) ? 8192 : 0);
        char* nxtE = smem + ((c & 1) ? 0 : 8192);
        if (c + 1 < 8) EWRITE(c + 1, nxtE);
        PVSTEP(c, curE);
        __syncthreads();
    }

    // ---- CT exchange, write ctx in universal tile layout ----
    const int dt = w & 3;
    if (khf == 1) {
        #pragma unroll
        for (int i = 0; i < 4; ++i) CT[(kg * 4 + i) * 64 + dt * 16 + r] = acc[i];
    }
    __syncthreads();
    if (khf == 0) {
        const int b_ = bh >> 4, h = bh & 15;
        const size_t base = (size_t)(b_ * 128 + blockIdx.x) * 16384
                          + (size_t)(h * 2 + (dt >> 1)) * 512;
        #pragma unroll
        for (int i = 0; i < 4; ++i) {
            const int lrow = kg * 4 + i;
            const float val = acc[i] + CT[lrow * 64 + dt * 16 + r];
            ctxt[base + ((((dt * 2 + (r >> 3)) & 3) * 16 + lrow) * 8) + (r & 7)]
                = f2bf(val);
        }
    }

    // ---- attn stream-out: after the last barrier ----
    #pragma unroll
    for (int rr = 0; rr < 2; ++rr) {
        const int row = w + 8 * rr;
        const float iv = inv[rr];
        float* arow = attn + ((size_t)bh * SEQ + q0 + row) * SEQ + lane * 4;
        #pragma unroll
        for (int c = 0; c < 8; ++c) {
            f32x4 pv;
            pv[0] = __uint_as_float(u[rr][c * 4 + 0]) * iv;
            pv[1] = __uint_as_float(u[rr][c * 4 + 1]) * iv;
            pv[2] = __uint_as_float(u[rr][c * 4 + 2]) * iv;
            pv[3] = __uint_as_float(u[rr][c * 4 + 3]) * iv;
            __builtin_nontemporal_store(
                pv, reinterpret_cast<f32x4*>(arow + c * 256));
        }
    }
}

// ---------------- K4: out = ctx @ wo^T + bo, tiled A and B ------------------
__global__ __launch_bounds__(256) void out_mfma(
    const short* __restrict__ ctxt, const short* __restrict__ wob,
    const float* __restrict__ bo, float* __restrict__ out)
{
    const int tid = threadIdx.x;
    const int w_  = tid >> 6, lane = tid & 63;
    const int r   = lane & 15, kg = lane >> 4;
    const int m_base = blockIdx.x * 128 + w_ * 32;
    const int n_base = blockIdx.y * 64;
    const int mtile0 = blockIdx.x * 8 + w_ * 2;
    const int ntile0 = blockIdx.y * 4;

    f32x4 acc[2][4] = {};

    for (int ks = 0; ks < 32; ++ks) {
        short8 a0 = ld8(ctxt + (size_t)mtile0 * 16384 + ks * 512 + lane * 8);
        short8 a1 = ld8(ctxt + (size_t)(mtile0 + 1) * 16384 + ks * 512 + lane * 8);
        #pragma unroll
        for (int nf = 0; nf < 4; ++nf) {
            short8 b = ld8(wob + (size_t)(ntile0 + nf) * 16384 + ks * 512 + lane * 8);
            acc[0][nf] = MFMA(a0, b, acc[0][nf]);
            acc[1][nf] = MFMA(a1, b, acc[1][nf]);
        }
    }

    #pragma unroll
    for (int mf = 0; mf < 2; ++mf)
        #pragma unroll
        for (int nf = 0; nf < 4; ++nf)
            #pragma unroll
            for (int i = 0; i < 4; ++i) {
                const int m  = m_base + mf * 16 + kg * 4 + i;
                const int nn = n_base + nf * 16 + r;
                out[(size_t)m * DIMN + nn] = acc[mf][nf][i] + bo[nn];
            }
}

extern "C" void kernel_launch(void* const* d_in, const int* in_sizes, int n_in,
                              void* d_out, int out_size, void* d_ws, size_t ws_size,
                              hipStream_t stream) {
    const float* x  = (const float*)d_in[0];
    const float* wq = (const float*)d_in[1];
    const float* bq = (const float*)d_in[2];
    const float* wk = (const float*)d_in[3];
    const float* bk = (const float*)d_in[4];
    const float* wv = (const float*)d_in[5];
    const float* bv = (const float*)d_in[6];
    const float* wo = (const float*)d_in[7];
    const float* bo = (const float*)d_in[8];

    float* out  = (float*)d_out;
    float* attn = out + (size_t)MROWS * DIMN;   // 512 MB region, written by fused_attn

    // --- scratch that dies before fused_attn runs: lives in the attn region ---
    short* xhi = (short*)attn;
    short* xlo = xhi + (size_t)MROWS * DIMN;
    short* wqh = xlo + (size_t)MROWS * DIMN;
    short* wql = wqh + (size_t)DIMN * DIMN;
    short* wkh = wql + (size_t)DIMN * DIMN;
    short* wkl = wkh + (size_t)DIMN * DIMN;
    short* wvb = wkl + (size_t)DIMN * DIMN;

    // --- scratch that must survive into/past fused_attn: lives in d_ws ---
    const size_t QKV = (size_t)BHN * SEQ * HD;  // 4,194,304
    short* qhi = (short*)d_ws;
    short* qlo = qhi + QKV;
    short* khi = qlo + QKV;
    short* klo = khi + QKV;
    short* vt  = klo + QKV;
    short* ctx = vt  + QKV;
    short* wob = ctx + QKV;

    conv_hilo_t<<<2048, 256, 0, stream>>>(x,  xhi, xlo, MROWS);
    conv_hilo_t<<<1024, 256, 0, stream>>>(wq, wqh, wql, DIMN);
    conv_hilo_t<<<1024, 256, 0, stream>>>(wk, wkh, wkl, DIMN);
    conv_bf16_t<<<1024, 256, 0, stream>>>(wv, wvb, DIMN);
    conv_bf16_t<<<1024, 256, 0, stream>>>(wo, wob, DIMN);

    qk_mfma<<<dim3(MROWS / 128, DIMN / 64, 2), 256, 0, stream>>>(
        xhi, xlo, wqh, wql, bq, wkh, wkl, bk, qhi, qlo, khi, klo);
    v_mfma<<<dim3(MROWS / 128, DIMN / 64), 256, 0, stream>>>(
        xhi, xlo, wvb, bv, vt);

    fused_attn<<<dim3(SEQ / QROWS, BHN), 512, 0, stream>>>(
        qhi, qlo, khi, klo, vt, attn, ctx);

    out_mfma<<<dim3(MROWS / 128, DIMN / 64), 256, 0, stream>>>(ctx, wob, bo, out);
}

// Round 14
// 428.044 us; speedup vs baseline: 2.7481x; 1.0231x over previous
//
#include <hip/hip_runtime.h>
#include <hip/hip_bf16.h>

#define DIMN 1024
#define NH 16
#define HD 64
#define SEQ 2048
#define BATCH 2
#define BHN (BATCH*NH)        // 32
#define MROWS (BATCH*SEQ)     // 4096
#define KKEEP 409
#define SCALEF 0.125f
#define QROWS 16              // q-rows per block

typedef __attribute__((ext_vector_type(8))) short short8;
typedef __attribute__((ext_vector_type(4))) short short4v;
typedef __attribute__((ext_vector_type(4))) float f32x4;

#define MFMA(a,b,c) __builtin_amdgcn_mfma_f32_16x16x32_bf16(a,b,c,0,0,0)

// ---- Universal MFMA-fragment tile layout for [rows][1024] operands:
// T(m,k) = (m>>4)*16384 + (k>>5)*512 + (((k>>3)&3)*16 + (m&15))*8 + (k&7)
// A wave's fragment load (16 rows x 8 k-elems) is one contiguous 1KB block.

static __device__ __forceinline__ short f2bf(float f) {
    __hip_bfloat16 h = __float2bfloat16(f);
    return *reinterpret_cast<short*>(&h);
}
static __device__ __forceinline__ float bf2f(short s) {
    __hip_bfloat16 h = *reinterpret_cast<__hip_bfloat16*>(&s);
    return __bfloat162float(h);
}
static __device__ __forceinline__ short8 ld8(const short* p) {
    return *reinterpret_cast<const short8*>(p);
}
static __device__ __forceinline__ float keyf(unsigned u) {
    unsigned fu = (u & 0x80000000u) ? (u ^ 0x80000000u) : ~u;
    return __uint_as_float(fu);
}
static __device__ __forceinline__ size_t tidx(int row, int k) {
    return (size_t)(row >> 4) * 16384 + (size_t)(k >> 5) * 512
         + ((((k >> 3) & 3) * 16 + (row & 15)) * 8) + (k & 7);
}

// ---------------- K0a: fp32 -> (hi, lo) bf16 pair, TILED output ------------
__global__ void conv_hilo_t(const float* __restrict__ in,
                            short* __restrict__ hi, short* __restrict__ lo, int rows) {
    const int total = rows * 256;     // 4 elems per thread
    for (int idx = blockIdx.x * blockDim.x + threadIdx.x; idx < total;
         idx += gridDim.x * blockDim.x) {
        const int row = idx >> 8;
        const int k = (idx & 255) * 4;
        float4 v = *reinterpret_cast<const float4*>(in + (size_t)row * DIMN + k);
        short4v h, l;
        #pragma unroll
        for (int j = 0; j < 4; ++j) {
            float f = (&v.x)[j];
            short hb = f2bf(f);
            h[j] = hb;
            l[j] = f2bf(f - bf2f(hb));
        }
        const size_t o = tidx(row, k);
        *reinterpret_cast<short4v*>(hi + o) = h;
        *reinterpret_cast<short4v*>(lo + o) = l;
    }
}

// ---------------- K0b: fp32 -> bf16, TILED output ---------------------------
__global__ void conv_bf16_t(const float* __restrict__ in,
                            short* __restrict__ out, int rows) {
    const int total = rows * 256;
    for (int idx = blockIdx.x * blockDim.x + threadIdx.x; idx < total;
         idx += gridDim.x * blockDim.x) {
        const int row = idx >> 8;
        const int k = (idx & 255) * 4;
        float4 v = *reinterpret_cast<const float4*>(in + (size_t)row * DIMN + k);
        short4v o;
        o[0] = f2bf(v.x); o[1] = f2bf(v.y); o[2] = f2bf(v.z); o[3] = f2bf(v.w);
        *reinterpret_cast<short4v*>(out + tidx(row, k)) = o;
    }
}

// ---------------- K1: Q/K projection, hi/lo precision, tiled in+out --------
__global__ __launch_bounds__(256) void qk_mfma(
    const short* __restrict__ xh, const short* __restrict__ xl,
    const short* __restrict__ wqh, const short* __restrict__ wql, const float* __restrict__ bq,
    const short* __restrict__ wkh, const short* __restrict__ wkl, const float* __restrict__ bk,
    short* __restrict__ qhi, short* __restrict__ qlo,
    short* __restrict__ khi, short* __restrict__ klo)
{
    const int z = blockIdx.z;
    const short* wh = z ? wkh : wqh;
    const short* wl = z ? wkl : wql;
    const float* bias = z ? bk : bq;
    short* dhi = z ? khi : qhi;
    short* dlo = z ? klo : qlo;

    const int tid  = threadIdx.x;
    const int wv_  = tid >> 6, lane = tid & 63;
    const int r    = lane & 15, kg = lane >> 4;
    const int m_base = blockIdx.x * 128 + wv_ * 32;
    const int n_base = blockIdx.y * 64;
    const int mtile0 = blockIdx.x * 8 + wv_ * 2;
    const int ntile0 = blockIdx.y * 4;

    f32x4 acc[2][4] = {};

    for (int ks = 0; ks < 32; ++ks) {
        short8 ah0 = ld8(xh + (size_t)mtile0 * 16384 + ks * 512 + lane * 8);
        short8 al0 = ld8(xl + (size_t)mtile0 * 16384 + ks * 512 + lane * 8);
        short8 ah1 = ld8(xh + (size_t)(mtile0 + 1) * 16384 + ks * 512 + lane * 8);
        short8 al1 = ld8(xl + (size_t)(mtile0 + 1) * 16384 + ks * 512 + lane * 8);
        #pragma unroll
        for (int nf = 0; nf < 4; ++nf) {
            short8 bh = ld8(wh + (size_t)(ntile0 + nf) * 16384 + ks * 512 + lane * 8);
            short8 bl = ld8(wl + (size_t)(ntile0 + nf) * 16384 + ks * 512 + lane * 8);
            acc[0][nf] = MFMA(ah0, bh, acc[0][nf]);
            acc[0][nf] = MFMA(ah0, bl, acc[0][nf]);
            acc[0][nf] = MFMA(al0, bh, acc[0][nf]);
            acc[1][nf] = MFMA(ah1, bh, acc[1][nf]);
            acc[1][nf] = MFMA(ah1, bl, acc[1][nf]);
            acc[1][nf] = MFMA(al1, bh, acc[1][nf]);
        }
    }

    const int h = blockIdx.y;
    #pragma unroll
    for (int mf = 0; mf < 2; ++mf)
        #pragma unroll
        for (int nf = 0; nf < 4; ++nf)
            #pragma unroll
            for (int i = 0; i < 4; ++i) {
                const int m  = m_base + mf * 16 + kg * 4 + i;
                const int nn = n_base + nf * 16 + r;
                const float val = acc[mf][nf][i] + bias[nn];
                const int b_ = m >> 11, s = m & 2047;
                const int hd = nf * 16 + r;
                const size_t idx = (size_t)(b_ * NH + h) * 131072
                    + (size_t)(s >> 4) * 1024 + (hd >> 5) * 512
                    + ((((hd >> 3) & 3) * 16 + (s & 15)) * 8) + (hd & 7);
                const short hb = f2bf(val);
                dhi[idx] = hb;
                dlo[idx] = f2bf(val - bf2f(hb));
            }
}

// ---------------- K2: V projection (2-MFMA), tiled in, tiled V^T out -------
__global__ __launch_bounds__(256) void v_mfma(
    const short* __restrict__ xh, const short* __restrict__ xl,
    const short* __restrict__ wvb, const float* __restrict__ bv,
    short* __restrict__ vt)
{
    const int tid  = threadIdx.x;
    const int wv_  = tid >> 6, lane = tid & 63;
    const int r    = lane & 15, kg = lane >> 4;
    const int m_base = blockIdx.x * 128 + wv_ * 32;
    const int n_base = blockIdx.y * 64;
    const int mtile0 = blockIdx.x * 8 + wv_ * 2;
    const int ntile0 = blockIdx.y * 4;

    f32x4 acc[2][4] = {};

    for (int ks = 0; ks < 32; ++ks) {
        short8 ah0 = ld8(xh + (size_t)mtile0 * 16384 + ks * 512 + lane * 8);
        short8 al0 = ld8(xl + (size_t)mtile0 * 16384 + ks * 512 + lane * 8);
        short8 ah1 = ld8(xh + (size_t)(mtile0 + 1) * 16384 + ks * 512 + lane * 8);
        short8 al1 = ld8(xl + (size_t)(mtile0 + 1) * 16384 + ks * 512 + lane * 8);
        #pragma unroll
        for (int nf = 0; nf < 4; ++nf) {
            short8 b = ld8(wvb + (size_t)(ntile0 + nf) * 16384 + ks * 512 + lane * 8);
            acc[0][nf] = MFMA(ah0, b, acc[0][nf]);
            acc[0][nf] = MFMA(al0, b, acc[0][nf]);
            acc[1][nf] = MFMA(ah1, b, acc[1][nf]);
            acc[1][nf] = MFMA(al1, b, acc[1][nf]);
        }
    }

    const int h = blockIdx.y;
    #pragma unroll
    for (int mf = 0; mf < 2; ++mf)
        #pragma unroll
        for (int nf = 0; nf < 4; ++nf)
            #pragma unroll
            for (int i = 0; i < 4; ++i) {
                const int m  = m_base + mf * 16 + kg * 4 + i;
                const int nn = n_base + nf * 16 + r;
                const float val = acc[mf][nf][i] + bv[nn];
                const int b_ = m >> 11, s = m & 2047;
                const int hd = nf * 16 + r;
                const size_t idx = (size_t)(b_ * NH + h) * 131072
                    + (size_t)(hd >> 4) * 32768 + (size_t)(s >> 5) * 512
                    + ((((s >> 3) & 3) * 16 + (hd & 15)) * 8) + (s & 7);
                vt[idx] = f2bf(val);
            }
}

// ---------------- K3: fused scores + exact top-k + softmax + PV ------------
// 1-D grid, XCD-pinned: all 128 blocks of one (b,h) land on one XCD so K/V
// re-reads hit that XCD's private 4MB L2 instead of streaming from L3.
__global__ __launch_bounds__(512, 4) void fused_attn(
    const short* __restrict__ qh, const short* __restrict__ ql,
    const short* __restrict__ kh, const short* __restrict__ kl,
    const short* __restrict__ vtb, float* __restrict__ attn,
    short* __restrict__ ctxt)
{
    __shared__ __align__(16) char smem[32768];
    float* CT = (float*)(smem + 16384);

    const int tid = threadIdx.x;
    const int w   = tid >> 6, lane = tid & 63;
    const int r   = lane & 15, kg = lane >> 4;

    // XCD-pinned mapping: dispatch round-robins wgid over 8 XCDs.
    const int bid  = blockIdx.x;
    const int xcd  = bid & 7;
    const int slot = bid >> 3;
    const int bh   = xcd + 8 * (slot >> 7);   // 4 bh per XCD
    const int qt   = slot & 127;              // q-tile within bh
    const int q0   = qt * QROWS;

    // ---- Phase A ----
    const size_t qtbase = (size_t)bh * 131072 + (size_t)qt * 1024 + lane * 8;
    short8 a0h = ld8(qh + qtbase),       a0l = ld8(ql + qtbase);
    short8 a1h = ld8(qh + qtbase + 512), a1l = ld8(ql + qtbase + 512);

    unsigned u[2][32];

    auto STAGE = [&](int c, float* buf) {
        #pragma unroll
        for (int tt = 0; tt < 2; ++tt) {
            const int stile = c * 16 + w + 8 * tt;
            const size_t tb = (size_t)bh * 131072 + (size_t)stile * 1024 + lane * 8;
            short8 b0h = ld8(kh + tb);
            short8 b0l = ld8(kl + tb);
            short8 b1h = ld8(kh + tb + 512);
            short8 b1l = ld8(kl + tb + 512);
            f32x4 accA = {0.f, 0.f, 0.f, 0.f};
            f32x4 accB = {0.f, 0.f, 0.f, 0.f};
            accA = MFMA(a0h, b0h, accA);
            accB = MFMA(a1h, b1h, accB);
            accA = MFMA(a0h, b0l, accA);
            accB = MFMA(a1h, b1l, accB);
            accA = MFMA(a0l, b0h, accA);
            accB = MFMA(a1l, b1h, accB);
            const int j0c = (w + 8 * tt) * 16;
            #pragma unroll
            for (int i = 0; i < 4; ++i)
                buf[(kg * 4 + i) * 256 + j0c + r] = (accA[i] + accB[i]) * SCALEF;
        }
    };

    STAGE(0, (float*)smem);
    __syncthreads();
    #pragma unroll
    for (int c = 0; c < 8; ++c) {
        float* cur = (float*)(smem + ((c & 1) ? 16384 : 0));
        float* nxt = (float*)(smem + ((c & 1) ? 0 : 16384));
        if (c + 1 < 8) STAGE(c + 1, nxt);
        #pragma unroll
        for (int rr = 0; rr < 2; ++rr) {
            const float* src = cur + (w + 8 * rr) * 256;
            f32x4 v4 = *reinterpret_cast<const f32x4*>(src + lane * 4);
            #pragma unroll
            for (int q_ = 0; q_ < 4; ++q_) {
                unsigned fu = __float_as_uint(v4[q_]);
                u[rr][c * 4 + q_] = (fu & 0x80000000u) ? ~fu : (fu | 0x80000000u);
            }
        }
        __syncthreads();
    }

    // ---- Phase B-1: early-exit exact radix top-k + softmax ----
    float inv[2];
    #pragma unroll
    for (int rr = 0; rr < 2; ++rr) {
        unsigned cur = 0;
        for (int bit = 31; bit >= 0; --bit) {
            const unsigned cand = cur | (1u << bit);
            int cnt = 0;
            #pragma unroll
            for (int jj = 0; jj < 32; ++jj)
                cnt += __popcll(__ballot(u[rr][jj] >= cand));
            if (cnt >= KKEEP) {
                cur = cand;
                if (cnt == KKEEP) break;
            }
        }
        unsigned mu = 0;
        #pragma unroll
        for (int jj = 0; jj < 32; ++jj) mu = (u[rr][jj] > mu) ? u[rr][jj] : mu;
        #pragma unroll
        for (int off = 32; off; off >>= 1) {
            unsigned o = (unsigned)__shfl_xor((int)mu, off);
            mu = (o > mu) ? o : mu;
        }
        const float m = keyf(mu);
        float denom = 0.f;
        #pragma unroll
        for (int jj = 0; jj < 32; ++jj) {
            const unsigned ue = u[rr][jj];
            const float e = (ue >= cur) ? __expf(keyf(ue) - m) : 0.f;
            u[rr][jj] = __float_as_uint(e);
            denom += e;
        }
        #pragma unroll
        for (int off = 32; off; off >>= 1) denom += __shfl_xor(denom, off);
        inv[rr] = 1.0f / denom;
    }

    // ---- Phase C ----
    const int khf = w >> 2;
    const int swzw = (w & 7) << 4;
    const int swzr = (r & 7) << 4;
    f32x4 acc = {0.f, 0.f, 0.f, 0.f};

    auto EWRITE = [&](int c, char* Ebase) {
        #pragma unroll
        for (int rr = 0; rr < 2; ++rr) {
            const int row = w + 8 * rr;
            const float iv = inv[rr];
            short4v pb;
            pb[0] = f2bf(__uint_as_float(u[rr][c * 4 + 0]) * iv);
            pb[1] = f2bf(__uint_as_float(u[rr][c * 4 + 1]) * iv);
            pb[2] = f2bf(__uint_as_float(u[rr][c * 4 + 2]) * iv);
            pb[3] = f2bf(__uint_as_float(u[rr][c * 4 + 3]) * iv);
            *reinterpret_cast<short4v*>(
                Ebase + row * 512 + ((lane * 8) ^ swzw)) = pb;
        }
    };
    auto PVSTEP = [&](int c, const char* Ebase) {
        const size_t vbase = (size_t)bh * 131072 + (size_t)(w & 3) * 32768
                           + (size_t)(c * 8 + khf * 4) * 512 + lane * 8;
        const char* Eb2 = Ebase + r * 512;
        #pragma unroll
        for (int ks = 0; ks < 4; ++ks) {
            const int kk = khf * 4 + ks;
            short8 pa = *reinterpret_cast<const short8*>(
                Eb2 + ((kk * 64 + kg * 16) ^ swzr));
            short8 vb = ld8(vtb + vbase + ks * 512);
            acc = MFMA(pa, vb, acc);
        }
    };

    EWRITE(0, smem);
    __syncthreads();
    #pragma unroll
    for (int c = 0; c < 8; ++c) {
        char* curE = smem + ((c & 1) ? 8192 : 0);
        char* nxtE = smem + ((c & 1) ? 0 : 8192);
        if (c + 1 < 8) EWRITE(c + 1, nxtE);
        PVSTEP(c, curE);
        __syncthreads();
    }

    // ---- CT exchange, write ctx in universal tile layout ----
    const int dt = w & 3;
    if (khf == 1) {
        #pragma unroll
        for (int i = 0; i < 4; ++i) CT[(kg * 4 + i) * 64 + dt * 16 + r] = acc[i];
    }
    __syncthreads();
    if (khf == 0) {
        const int b_ = bh >> 4, h = bh & 15;
        const size_t base = (size_t)(b_ * 128 + qt) * 16384
                          + (size_t)(h * 2 + (dt >> 1)) * 512;
        #pragma unroll
        for (int i = 0; i < 4; ++i) {
            const int lrow = kg * 4 + i;
            const float val = acc[i] + CT[lrow * 64 + dt * 16 + r];
            ctxt[base + ((((dt * 2 + (r >> 3)) & 3) * 16 + lrow) * 8) + (r & 7)]
                = f2bf(val);
        }
    }

    // ---- attn stream-out: after the last barrier ----
    #pragma unroll
    for (int rr = 0; rr < 2; ++rr) {
        const int row = w + 8 * rr;
        const float iv = inv[rr];
        float* arow = attn + ((size_t)bh * SEQ + q0 + row) * SEQ + lane * 4;
        #pragma unroll
        for (int c = 0; c < 8; ++c) {
            f32x4 pv;
            pv[0] = __uint_as_float(u[rr][c * 4 + 0]) * iv;
            pv[1] = __uint_as_float(u[rr][c * 4 + 1]) * iv;
            pv[2] = __uint_as_float(u[rr][c * 4 + 2]) * iv;
            pv[3] = __uint_as_float(u[rr][c * 4 + 3]) * iv;
            __builtin_nontemporal_store(
                pv, reinterpret_cast<f32x4*>(arow + c * 256));
        }
    }
}

// ---------------- K4: out = ctx @ wo^T + bo, tiled A and B ------------------
__global__ __launch_bounds__(256) void out_mfma(
    const short* __restrict__ ctxt, const short* __restrict__ wob,
    const float* __restrict__ bo, float* __restrict__ out)
{
    const int tid = threadIdx.x;
    const int w_  = tid >> 6, lane = tid & 63;
    const int r   = lane & 15, kg = lane >> 4;
    const int m_base = blockIdx.x * 128 + w_ * 32;
    const int n_base = blockIdx.y * 64;
    const int mtile0 = blockIdx.x * 8 + w_ * 2;
    const int ntile0 = blockIdx.y * 4;

    f32x4 acc[2][4] = {};

    for (int ks = 0; ks < 32; ++ks) {
        short8 a0 = ld8(ctxt + (size_t)mtile0 * 16384 + ks * 512 + lane * 8);
        short8 a1 = ld8(ctxt + (size_t)(mtile0 + 1) * 16384 + ks * 512 + lane * 8);
        #pragma unroll
        for (int nf = 0; nf < 4; ++nf) {
            short8 b = ld8(wob + (size_t)(ntile0 + nf) * 16384 + ks * 512 + lane * 8);
            acc[0][nf] = MFMA(a0, b, acc[0][nf]);
            acc[1][nf] = MFMA(a1, b, acc[1][nf]);
        }
    }

    #pragma unroll
    for (int mf = 0; mf < 2; ++mf)
        #pragma unroll
        for (int nf = 0; nf < 4; ++nf)
            #pragma unroll
            for (int i = 0; i < 4; ++i) {
                const int m  = m_base + mf * 16 + kg * 4 + i;
                const int nn = n_base + nf * 16 + r;
                out[(size_t)m * DIMN + nn] = acc[mf][nf][i] + bo[nn];
            }
}

extern "C" void kernel_launch(void* const* d_in, const int* in_sizes, int n_in,
                              void* d_out, int out_size, void* d_ws, size_t ws_size,
                              hipStream_t stream) {
    const float* x  = (const float*)d_in[0];
    const float* wq = (const float*)d_in[1];
    const float* bq = (const float*)d_in[2];
    const float* wk = (const float*)d_in[3];
    const float* bk = (const float*)d_in[4];
    const float* wv = (const float*)d_in[5];
    const float* bv = (const float*)d_in[6];
    const float* wo = (const float*)d_in[7];
    const float* bo = (const float*)d_in[8];

    float* out  = (float*)d_out;
    float* attn = out + (size_t)MROWS * DIMN;   // 512 MB region, written by fused_attn

    // --- scratch that dies before fused_attn runs: lives in the attn region ---
    short* xhi = (short*)attn;
    short* xlo = xhi + (size_t)MROWS * DIMN;
    short* wqh = xlo + (size_t)MROWS * DIMN;
    short* wql = wqh + (size_t)DIMN * DIMN;
    short* wkh = wql + (size_t)DIMN * DIMN;
    short* wkl = wkh + (size_t)DIMN * DIMN;
    short* wvb = wkl + (size_t)DIMN * DIMN;

    // --- scratch that must survive into/past fused_attn: lives in d_ws ---
    const size_t QKV = (size_t)BHN * SEQ * HD;  // 4,194,304
    short* qhi = (short*)d_ws;
    short* qlo = qhi + QKV;
    short* khi = qlo + QKV;
    short* klo = khi + QKV;
    short* vt  = klo + QKV;
    short* ctx = vt  + QKV;
    short* wob = ctx + QKV;

    conv_hilo_t<<<2048, 256, 0, stream>>>(x,  xhi, xlo, MROWS);
    conv_hilo_t<<<1024, 256, 0, stream>>>(wq, wqh, wql, DIMN);
    conv_hilo_t<<<1024, 256, 0, stream>>>(wk, wkh, wkl, DIMN);
    conv_bf16_t<<<1024, 256, 0, stream>>>(wv, wvb, DIMN);
    conv_bf16_t<<<1024, 256, 0, stream>>>(wo, wob, DIMN);

    qk_mfma<<<dim3(MROWS / 128, DIMN / 64, 2), 256, 0, stream>>>(
        xhi, xlo, wqh, wql, bq, wkh, wkl, bk, qhi, qlo, khi, klo);
    v_mfma<<<dim3(MROWS / 128, DIMN / 64), 256, 0, stream>>>(
        xhi, xlo, wvb, bv, vt);

    fused_attn<<<dim3(SEQ / QROWS * BHN), 512, 0, stream>>>(
        qhi, qlo, khi, klo, vt, attn, ctx);

    out_mfma<<<dim3(MROWS / 128, DIMN / 64), 256, 0, stream>>>(ctx, wob, bo, out);
}

// Round 15
// 408.784 us; speedup vs baseline: 2.8776x; 1.0471x over previous
//
#include <hip/hip_runtime.h>
#include <hip/hip_bf16.h>

#define DIMN 1024
#define NH 16
#define HD 64
#define SEQ 2048
#define BATCH 2
#define BHN (BATCH*NH)        // 32
#define MROWS (BATCH*SEQ)     // 4096
#define KKEEP 409
#define SCALEF 0.125f
#define QROWS 16              // q-rows per block

typedef __attribute__((ext_vector_type(8))) short short8;
typedef __attribute__((ext_vector_type(4))) short short4v;
typedef __attribute__((ext_vector_type(4))) float f32x4;

#define MFMA(a,b,c) __builtin_amdgcn_mfma_f32_16x16x32_bf16(a,b,c,0,0,0)

// ---- Universal MFMA-fragment tile layout for [rows][1024] operands:
// T(m,k) = (m>>4)*16384 + (k>>5)*512 + (((k>>3)&3)*16 + (m&15))*8 + (k&7)

static __device__ __forceinline__ short f2bf(float f) {
    __hip_bfloat16 h = __float2bfloat16(f);
    return *reinterpret_cast<short*>(&h);
}
static __device__ __forceinline__ float bf2f(short s) {
    __hip_bfloat16 h = *reinterpret_cast<__hip_bfloat16*>(&s);
    return __bfloat162float(h);
}
static __device__ __forceinline__ short8 ld8(const short* p) {
    return *reinterpret_cast<const short8*>(p);
}
static __device__ __forceinline__ float keyf(unsigned u) {
    unsigned fu = (u & 0x80000000u) ? (u ^ 0x80000000u) : ~u;
    return __uint_as_float(fu);
}
static __device__ __forceinline__ size_t tidx(int row, int k) {
    return (size_t)(row >> 4) * 16384 + (size_t)(k >> 5) * 512
         + ((((k >> 3) & 3) * 16 + (row & 15)) * 8) + (k & 7);
}

// ---------------- K0: ALL fp32->bf16 conversions in one launch --------------
static __device__ __forceinline__ void conv_hilo_body(
    const float* in, short* hi, short* lo, int rows) {
    const int total = rows * 256;
    for (int idx = blockIdx.x * blockDim.x + threadIdx.x; idx < total;
         idx += gridDim.x * blockDim.x) {
        const int row = idx >> 8;
        const int k = (idx & 255) * 4;
        float4 v = *reinterpret_cast<const float4*>(in + (size_t)row * DIMN + k);
        short4v h, l;
        #pragma unroll
        for (int j = 0; j < 4; ++j) {
            float f = (&v.x)[j];
            short hb = f2bf(f);
            h[j] = hb;
            l[j] = f2bf(f - bf2f(hb));
        }
        const size_t o = tidx(row, k);
        *reinterpret_cast<short4v*>(hi + o) = h;
        *reinterpret_cast<short4v*>(lo + o) = l;
    }
}
static __device__ __forceinline__ void conv_bf16_body(
    const float* in, short* out, int rows) {
    const int total = rows * 256;
    for (int idx = blockIdx.x * blockDim.x + threadIdx.x; idx < total;
         idx += gridDim.x * blockDim.x) {
        const int row = idx >> 8;
        const int k = (idx & 255) * 4;
        float4 v = *reinterpret_cast<const float4*>(in + (size_t)row * DIMN + k);
        short4v o;
        o[0] = f2bf(v.x); o[1] = f2bf(v.y); o[2] = f2bf(v.z); o[3] = f2bf(v.w);
        *reinterpret_cast<short4v*>(out + tidx(row, k)) = o;
    }
}
__global__ void conv_all(
    const float* __restrict__ x, const float* __restrict__ wq,
    const float* __restrict__ wk, const float* __restrict__ wv,
    const float* __restrict__ wo,
    short* __restrict__ xhi, short* __restrict__ xlo,
    short* __restrict__ wqh, short* __restrict__ wql,
    short* __restrict__ wkh, short* __restrict__ wkl,
    short* __restrict__ wvb, short* __restrict__ wob)
{
    switch (blockIdx.y) {
        case 0: conv_hilo_body(x,  xhi, xlo, MROWS); break;
        case 1: conv_hilo_body(wq, wqh, wql, DIMN);  break;
        case 2: conv_hilo_body(wk, wkh, wkl, DIMN);  break;
        case 3: conv_bf16_body(wv, wvb, DIMN);       break;
        default: conv_bf16_body(wo, wob, DIMN);      break;
    }
}

// ---------------- K1: Q/K/V projections, one launch (z=0 q, 1 k, 2 v) ------
__global__ __launch_bounds__(256) void qkv_mfma(
    const short* __restrict__ xh, const short* __restrict__ xl,
    const short* __restrict__ wqh, const short* __restrict__ wql, const float* __restrict__ bq,
    const short* __restrict__ wkh, const short* __restrict__ wkl, const float* __restrict__ bk,
    const short* __restrict__ wvb, const float* __restrict__ bv,
    short* __restrict__ qhi, short* __restrict__ qlo,
    short* __restrict__ khi, short* __restrict__ klo,
    short* __restrict__ vt)
{
    const int z = blockIdx.z;
    const int tid  = threadIdx.x;
    const int wv_  = tid >> 6, lane = tid & 63;
    const int r    = lane & 15, kg = lane >> 4;
    const int m_base = blockIdx.x * 128 + wv_ * 32;
    const int n_base = blockIdx.y * 64;
    const int mtile0 = blockIdx.x * 8 + wv_ * 2;
    const int ntile0 = blockIdx.y * 4;
    const int h = blockIdx.y;

    f32x4 acc[2][4] = {};

    if (z < 2) {
        const short* wh = z ? wkh : wqh;
        const short* wl = z ? wkl : wql;
        const float* bias = z ? bk : bq;
        short* dhi = z ? khi : qhi;
        short* dlo = z ? klo : qlo;

        for (int ks = 0; ks < 32; ++ks) {
            short8 ah0 = ld8(xh + (size_t)mtile0 * 16384 + ks * 512 + lane * 8);
            short8 al0 = ld8(xl + (size_t)mtile0 * 16384 + ks * 512 + lane * 8);
            short8 ah1 = ld8(xh + (size_t)(mtile0 + 1) * 16384 + ks * 512 + lane * 8);
            short8 al1 = ld8(xl + (size_t)(mtile0 + 1) * 16384 + ks * 512 + lane * 8);
            #pragma unroll
            for (int nf = 0; nf < 4; ++nf) {
                short8 bh = ld8(wh + (size_t)(ntile0 + nf) * 16384 + ks * 512 + lane * 8);
                short8 bl = ld8(wl + (size_t)(ntile0 + nf) * 16384 + ks * 512 + lane * 8);
                acc[0][nf] = MFMA(ah0, bh, acc[0][nf]);
                acc[0][nf] = MFMA(ah0, bl, acc[0][nf]);
                acc[0][nf] = MFMA(al0, bh, acc[0][nf]);
                acc[1][nf] = MFMA(ah1, bh, acc[1][nf]);
                acc[1][nf] = MFMA(ah1, bl, acc[1][nf]);
                acc[1][nf] = MFMA(al1, bh, acc[1][nf]);
            }
        }

        #pragma unroll
        for (int mf = 0; mf < 2; ++mf)
            #pragma unroll
            for (int nf = 0; nf < 4; ++nf)
                #pragma unroll
                for (int i = 0; i < 4; ++i) {
                    const int m  = m_base + mf * 16 + kg * 4 + i;
                    const int nn = n_base + nf * 16 + r;
                    const float val = acc[mf][nf][i] + bias[nn];
                    const int b_ = m >> 11, s = m & 2047;
                    const int hd = nf * 16 + r;
                    const size_t idx = (size_t)(b_ * NH + h) * 131072
                        + (size_t)(s >> 4) * 1024 + (hd >> 5) * 512
                        + ((((hd >> 3) & 3) * 16 + (s & 15)) * 8) + (hd & 7);
                    const short hb = f2bf(val);
                    dhi[idx] = hb;
                    dlo[idx] = f2bf(val - bf2f(hb));
                }
    } else {
        for (int ks = 0; ks < 32; ++ks) {
            short8 ah0 = ld8(xh + (size_t)mtile0 * 16384 + ks * 512 + lane * 8);
            short8 al0 = ld8(xl + (size_t)mtile0 * 16384 + ks * 512 + lane * 8);
            short8 ah1 = ld8(xh + (size_t)(mtile0 + 1) * 16384 + ks * 512 + lane * 8);
            short8 al1 = ld8(xl + (size_t)(mtile0 + 1) * 16384 + ks * 512 + lane * 8);
            #pragma unroll
            for (int nf = 0; nf < 4; ++nf) {
                short8 b = ld8(wvb + (size_t)(ntile0 + nf) * 16384 + ks * 512 + lane * 8);
                acc[0][nf] = MFMA(ah0, b, acc[0][nf]);
                acc[0][nf] = MFMA(al0, b, acc[0][nf]);
                acc[1][nf] = MFMA(ah1, b, acc[1][nf]);
                acc[1][nf] = MFMA(al1, b, acc[1][nf]);
            }
        }

        #pragma unroll
        for (int mf = 0; mf < 2; ++mf)
            #pragma unroll
            for (int nf = 0; nf < 4; ++nf)
                #pragma unroll
                for (int i = 0; i < 4; ++i) {
                    const int m  = m_base + mf * 16 + kg * 4 + i;
                    const int nn = n_base + nf * 16 + r;
                    const float val = acc[mf][nf][i] + bv[nn];
                    const int b_ = m >> 11, s = m & 2047;
                    const int hd = nf * 16 + r;
                    const size_t idx = (size_t)(b_ * NH + h) * 131072
                        + (size_t)(hd >> 4) * 32768 + (size_t)(s >> 5) * 512
                        + ((((s >> 3) & 3) * 16 + (hd & 15)) * 8) + (s & 7);
                    vt[idx] = f2bf(val);
                }
    }
}

// ---------------- K2: fused scores + exact top-k + softmax + PV ------------
// 512-col chunks (4 per row): 12 barriers/block instead of 20. LDS 64KB ->
// 2 blocks/CU. XCD-pinned 1-D grid. Same arithmetic as R13/R14 (bit-exact).
__global__ __launch_bounds__(512, 4) void fused_attn(
    const short* __restrict__ qh, const short* __restrict__ ql,
    const short* __restrict__ kh, const short* __restrict__ kl,
    const short* __restrict__ vtb, float* __restrict__ attn,
    short* __restrict__ ctxt)
{
    __shared__ __align__(16) char smem[65536];
    // Phase A: CB0 fp32[16][512] @0 (32KB), CB1 @32768
    // Phase C: E0 bf16[16][512] @0 (16KB), E1 @16384, CT fp32[16][64] @32768
    float* CT = (float*)(smem + 32768);

    const int tid = threadIdx.x;
    const int w   = tid >> 6, lane = tid & 63;
    const int r   = lane & 15, kg = lane >> 4;

    // XCD-pinned mapping
    const int bid  = blockIdx.x;
    const int xcd  = bid & 7;
    const int slot = bid >> 3;
    const int bh   = xcd + 8 * (slot >> 7);
    const int qt   = slot & 127;
    const int q0   = qt * QROWS;

    // ---- Phase A: S = SCALE*Q K^T, 4 chunks of 512 cols, pipelined ----
    const size_t qtbase = (size_t)bh * 131072 + (size_t)qt * 1024 + lane * 8;
    short8 a0h = ld8(qh + qtbase),       a0l = ld8(ql + qtbase);
    short8 a1h = ld8(qh + qtbase + 512), a1l = ld8(ql + qtbase + 512);

    unsigned u[2][32];

    auto STAGE = [&](int c, float* buf) {
        #pragma unroll
        for (int tt = 0; tt < 4; ++tt) {
            const int stile = c * 32 + w + 8 * tt;
            const size_t tb = (size_t)bh * 131072 + (size_t)stile * 1024 + lane * 8;
            short8 b0h = ld8(kh + tb);
            short8 b0l = ld8(kl + tb);
            short8 b1h = ld8(kh + tb + 512);
            short8 b1l = ld8(kl + tb + 512);
            f32x4 accA = {0.f, 0.f, 0.f, 0.f};
            f32x4 accB = {0.f, 0.f, 0.f, 0.f};
            accA = MFMA(a0h, b0h, accA);
            accB = MFMA(a1h, b1h, accB);
            accA = MFMA(a0h, b0l, accA);
            accB = MFMA(a1h, b1l, accB);
            accA = MFMA(a0l, b0h, accA);
            accB = MFMA(a1l, b1h, accB);
            const int j0c = (w + 8 * tt) * 16;
            #pragma unroll
            for (int i = 0; i < 4; ++i)
                buf[(kg * 4 + i) * 512 + j0c + r] = (accA[i] + accB[i]) * SCALEF;
        }
    };

    STAGE(0, (float*)smem);
    __syncthreads();
    #pragma unroll
    for (int c = 0; c < 4; ++c) {
        float* cur = (float*)(smem + ((c & 1) ? 32768 : 0));
        float* nxt = (float*)(smem + ((c & 1) ? 0 : 32768));
        if (c + 1 < 4) STAGE(c + 1, nxt);
        #pragma unroll
        for (int rr = 0; rr < 2; ++rr) {
            const float* src = cur + (w + 8 * rr) * 512;
            #pragma unroll
            for (int g = 0; g < 2; ++g) {
                f32x4 v4 = *reinterpret_cast<const f32x4*>(src + g * 256 + lane * 4);
                #pragma unroll
                for (int q_ = 0; q_ < 4; ++q_) {
                    unsigned fu = __float_as_uint(v4[q_]);
                    u[rr][c * 8 + g * 4 + q_] =
                        (fu & 0x80000000u) ? ~fu : (fu | 0x80000000u);
                }
            }
        }
        __syncthreads();
    }

    // ---- Phase B: early-exit exact radix top-k + softmax (regs only) ----
    float inv[2];
    #pragma unroll
    for (int rr = 0; rr < 2; ++rr) {
        unsigned cur = 0;
        for (int bit = 31; bit >= 0; --bit) {
            const unsigned cand = cur | (1u << bit);
            int cnt = 0;
            #pragma unroll
            for (int jj = 0; jj < 32; ++jj)
                cnt += __popcll(__ballot(u[rr][jj] >= cand));
            if (cnt >= KKEEP) {
                cur = cand;
                if (cnt == KKEEP) break;
            }
        }
        unsigned mu = 0;
        #pragma unroll
        for (int jj = 0; jj < 32; ++jj) mu = (u[rr][jj] > mu) ? u[rr][jj] : mu;
        #pragma unroll
        for (int off = 32; off; off >>= 1) {
            unsigned o = (unsigned)__shfl_xor((int)mu, off);
            mu = (o > mu) ? o : mu;
        }
        const float m = keyf(mu);
        float denom = 0.f;
        #pragma unroll
        for (int jj = 0; jj < 32; ++jj) {
            const unsigned ue = u[rr][jj];
            const float e = (ue >= cur) ? __expf(keyf(ue) - m) : 0.f;
            u[rr][jj] = __float_as_uint(e);
            denom += e;
        }
        #pragma unroll
        for (int off = 32; off; off >>= 1) denom += __shfl_xor(denom, off);
        inv[rr] = 1.0f / denom;
    }

    // ---- Phase C: 4x 512-col chunks; E double-buffered; LDS writes only ----
    const int khf = w >> 2;
    const int swzw = (w & 7) << 4;
    const int swzr = (r & 7) << 4;
    f32x4 acc = {0.f, 0.f, 0.f, 0.f};

    auto EWRITE = [&](int c, char* Ebase) {
        #pragma unroll
        for (int rr = 0; rr < 2; ++rr) {
            const int row = w + 8 * rr;
            const float iv = inv[rr];
            #pragma unroll
            for (int g = 0; g < 2; ++g) {
                short4v pb;
                pb[0] = f2bf(__uint_as_float(u[rr][c * 8 + g * 4 + 0]) * iv);
                pb[1] = f2bf(__uint_as_float(u[rr][c * 8 + g * 4 + 1]) * iv);
                pb[2] = f2bf(__uint_as_float(u[rr][c * 8 + g * 4 + 2]) * iv);
                pb[3] = f2bf(__uint_as_float(u[rr][c * 8 + g * 4 + 3]) * iv);
                *reinterpret_cast<short4v*>(
                    Ebase + row * 1024 + ((g * 512 + lane * 8) ^ swzw)) = pb;
            }
        }
    };
    auto PVSTEP = [&](int c, const char* Ebase) {
        const size_t vbase = (size_t)bh * 131072 + (size_t)(w & 3) * 32768
                           + (size_t)(c * 16 + khf * 8) * 512 + lane * 8;
        const char* Eb2 = Ebase + r * 1024;
        #pragma unroll
        for (int ks = 0; ks < 8; ++ks) {
            const int kk = khf * 8 + ks;
            short8 pa = *reinterpret_cast<const short8*>(
                Eb2 + ((kk * 64 + kg * 16) ^ swzr));
            short8 vb = ld8(vtb + vbase + ks * 512);
            acc = MFMA(pa, vb, acc);
        }
    };

    EWRITE(0, smem);
    __syncthreads();
    #pragma unroll
    for (int c = 0; c < 4; ++c) {
        char* curE = smem + ((c & 1) ? 16384 : 0);
        char* nxtE = smem + ((c & 1) ? 0 : 16384);
        if (c + 1 < 4) EWRITE(c + 1, nxtE);
        PVSTEP(c, curE);
        __syncthreads();
    }

    // ---- CT exchange, write ctx in universal tile layout ----
    const int dt = w & 3;
    if (khf == 1) {
        #pragma unroll
        for (int i = 0; i < 4; ++i) CT[(kg * 4 + i) * 64 + dt * 16 + r] = acc[i];
    }
    __syncthreads();
    if (khf == 0) {
        const int b_ = bh >> 4, h = bh & 15;
        const size_t base = (size_t)(b_ * 128 + qt) * 16384
                          + (size_t)(h * 2 + (dt >> 1)) * 512;
        #pragma unroll
        for (int i = 0; i < 4; ++i) {
            const int lrow = kg * 4 + i;
            const float val = acc[i] + CT[lrow * 64 + dt * 16 + r];
            ctxt[base + ((((dt * 2 + (r >> 3)) & 3) * 16 + lrow) * 8) + (r & 7)]
                = f2bf(val);
        }
    }

    // ---- attn stream-out: after the last barrier, fire-and-forget ----
    #pragma unroll
    for (int rr = 0; rr < 2; ++rr) {
        const int row = w + 8 * rr;
        const float iv = inv[rr];
        float* arow = attn + ((size_t)bh * SEQ + q0 + row) * SEQ + lane * 4;
        #pragma unroll
        for (int c = 0; c < 4; ++c)
            #pragma unroll
            for (int g = 0; g < 2; ++g) {
                f32x4 pv;
                pv[0] = __uint_as_float(u[rr][c * 8 + g * 4 + 0]) * iv;
                pv[1] = __uint_as_float(u[rr][c * 8 + g * 4 + 1]) * iv;
                pv[2] = __uint_as_float(u[rr][c * 8 + g * 4 + 2]) * iv;
                pv[3] = __uint_as_float(u[rr][c * 8 + g * 4 + 3]) * iv;
                __builtin_nontemporal_store(
                    pv, reinterpret_cast<f32x4*>(arow + c * 512 + g * 256));
            }
    }
}

// ---------------- K3: out = ctx @ wo^T + bo, tiled A and B ------------------
__global__ __launch_bounds__(256) void out_mfma(
    const short* __restrict__ ctxt, const short* __restrict__ wob,
    const float* __restrict__ bo, float* __restrict__ out)
{
    const int tid = threadIdx.x;
    const int w_  = tid >> 6, lane = tid & 63;
    const int r   = lane & 15, kg = lane >> 4;
    const int m_base = blockIdx.x * 128 + w_ * 32;
    const int n_base = blockIdx.y * 64;
    const int mtile0 = blockIdx.x * 8 + w_ * 2;
    const int ntile0 = blockIdx.y * 4;

    f32x4 acc[2][4] = {};

    for (int ks = 0; ks < 32; ++ks) {
        short8 a0 = ld8(ctxt + (size_t)mtile0 * 16384 + ks * 512 + lane * 8);
        short8 a1 = ld8(ctxt + (size_t)(mtile0 + 1) * 16384 + ks * 512 + lane * 8);
        #pragma unroll
        for (int nf = 0; nf < 4; ++nf) {
            short8 b = ld8(wob + (size_t)(ntile0 + nf) * 16384 + ks * 512 + lane * 8);
            acc[0][nf] = MFMA(a0, b, acc[0][nf]);
            acc[1][nf] = MFMA(a1, b, acc[1][nf]);
        }
    }

    #pragma unroll
    for (int mf = 0; mf < 2; ++mf)
        #pragma unroll
        for (int nf = 0; nf < 4; ++nf)
            #pragma unroll
            for (int i = 0; i < 4; ++i) {
                const int m  = m_base + mf * 16 + kg * 4 + i;
                const int nn = n_base + nf * 16 + r;
                out[(size_t)m * DIMN + nn] = acc[mf][nf][i] + bo[nn];
            }
}

extern "C" void kernel_launch(void* const* d_in, const int* in_sizes, int n_in,
                              void* d_out, int out_size, void* d_ws, size_t ws_size,
                              hipStream_t stream) {
    const float* x  = (const float*)d_in[0];
    const float* wq = (const float*)d_in[1];
    const float* bq = (const float*)d_in[2];
    const float* wk = (const float*)d_in[3];
    const float* bk = (const float*)d_in[4];
    const float* wv = (const float*)d_in[5];
    const float* bv = (const float*)d_in[6];
    const float* wo = (const float*)d_in[7];
    const float* bo = (const float*)d_in[8];

    float* out  = (float*)d_out;
    float* attn = out + (size_t)MROWS * DIMN;   // 512 MB region, written by fused_attn

    // --- scratch that dies before fused_attn runs: lives in the attn region ---
    short* xhi = (short*)attn;
    short* xlo = xhi + (size_t)MROWS * DIMN;
    short* wqh = xlo + (size_t)MROWS * DIMN;
    short* wql = wqh + (size_t)DIMN * DIMN;
    short* wkh = wql + (size_t)DIMN * DIMN;
    short* wkl = wkh + (size_t)DIMN * DIMN;
    short* wvb = wkl + (size_t)DIMN * DIMN;

    // --- scratch that must survive into/past fused_attn: lives in d_ws ---
    const size_t QKV = (size_t)BHN * SEQ * HD;  // 4,194,304
    short* qhi = (short*)d_ws;
    short* qlo = qhi + QKV;
    short* khi = qlo + QKV;
    short* klo = khi + QKV;
    short* vt  = klo + QKV;
    short* ctx = vt  + QKV;
    short* wob = ctx + QKV;

    conv_all<<<dim3(512, 5), 256, 0, stream>>>(
        x, wq, wk, wv, wo, xhi, xlo, wqh, wql, wkh, wkl, wvb, wob);

    qkv_mfma<<<dim3(MROWS / 128, DIMN / 64, 3), 256, 0, stream>>>(
        xhi, xlo, wqh, wql, bq, wkh, wkl, bk, wvb, bv,
        qhi, qlo, khi, klo, vt);

    fused_attn<<<dim3(SEQ / QROWS * BHN), 512, 0, stream>>>(
        qhi, qlo, khi, klo, vt, attn, ctx);

    out_mfma<<<dim3(MROWS / 128, DIMN / 64), 256, 0, stream>>>(ctx, wob, bo, out);
}